// Round 9
// baseline (5563.420 us; speedup 1.0000x reference)
//
#include <hip/hip_runtime.h>
#include <stdint.h>
#include <stddef.h>

#define NBATCH 32
#define HW     16384      // 128*128
#define CCH    128

typedef short bf16x8 __attribute__((ext_vector_type(8)));
typedef float f32x4  __attribute__((ext_vector_type(4)));

__device__ __forceinline__ float bf2f(unsigned short u){
    union { unsigned int i; float f; } v; v.i = ((unsigned int)u) << 16; return v.f;
}
__device__ __forceinline__ unsigned short f2bf(float f){
    union { float f; unsigned int i; } v; v.f = f;
    unsigned int x = v.i;
    x += 0x7fffu + ((x >> 16) & 1u);   // round-to-nearest-even
    return (unsigned short)(x >> 16);
}
__device__ __forceinline__ unsigned int h16(uint2 u, int j){
    unsigned int v = (j & 2) ? u.y : u.x;
    return (j & 1) ? (v >> 16) : (v & 0xffffu);
}

// ---------------------------------------------------------------- weight prep:
// per conv: [NCH][2(hi/lo)][128][32] bf16, PLAIN (no swizzle). 8192 shorts/chunk.
// segments (shorts): wa1@0(1) wb1@8192(1) wc1@16384(5) wa2@57344(4) wb2@90112(4)
// wc2@122880(8) wa3@188416(4) wb3@221184(4) wc3@253952(8). total 319488.
#define WPREP_TOTAL 319488
__global__ __launch_bounds__(256) void k_prep(
    const float* __restrict__ w11, const float* __restrict__ w12, const float* __restrict__ w13,
    const float* __restrict__ w21, const float* __restrict__ w22, const float* __restrict__ w23,
    const float* __restrict__ w31, const float* __restrict__ w32, const float* __restrict__ w33,
    unsigned short* __restrict__ wp)
{
    int i = blockIdx.x*256 + threadIdx.x;
    if(i >= WPREP_TOTAL) return;
    const float* src; int K, mode, base;   // mode: 0=normal 1=dup16 2=wc1
    if     (i < 8192)  { src=w11; K=16;  mode=1; base=0;      }
    else if(i < 16384) { src=w12; K=16;  mode=1; base=8192;   }
    else if(i < 57344) { src=w13; K=144; mode=2; base=16384;  }
    else if(i < 90112) { src=w21; K=128; mode=0; base=57344;  }
    else if(i < 122880){ src=w22; K=128; mode=0; base=90112;  }
    else if(i < 188416){ src=w23; K=256; mode=0; base=122880; }
    else if(i < 221184){ src=w31; K=128; mode=0; base=188416; }
    else if(i < 253952){ src=w32; K=128; mode=0; base=221184; }
    else               { src=w33; K=256; mode=0; base=253952; }
    int j  = i - base;
    int ck = j >> 13;
    int jj = j & 8191;
    int half = jj >> 12;
    int row  = (jj >> 5) & 127;
    int c    = jj & 31;
    int col  = (mode==1) ? (c & 15)
             : (mode==2) ? (ck < 4 ? ck*32 + c : 128 + (c & 15))
             :             ck*32 + c;
    float v = src[row*K + col];
    unsigned short hi = f2bf(v);
    wp[i] = half ? f2bf(v - bf2f(hi)) : hi;
}

// ---------------------------------------------------------------- X2 -> hw-major hi/lo (plain):
// X2b[b][ht 64][hwin 256][32 c] bf16; c 0-15 = hi, 16-31 = lo.
__global__ __launch_bounds__(256) void k_xprep(const float* __restrict__ X2, unsigned short* __restrict__ X2b){
    const int ht = blockIdx.x, b = blockIdx.y, t = threadIdx.x;
    const float* src = X2 + (size_t)b*16*HW + ht*256 + t;
    unsigned short hv[16], lv[16];
    #pragma unroll
    for(int c=0;c<16;c++){
        float v = src[(size_t)c*HW];
        hv[c] = f2bf(v);
        lv[c] = f2bf(v - bf2f(hv[c]));
    }
    unsigned short* dst = X2b + ((size_t)b*64 + ht)*8192 + t*32;
    uint4 a,b2,c4,d;
    a.x  = hv[0] |(hv[1] <<16); a.y  = hv[2] |(hv[3] <<16); a.z  = hv[4] |(hv[5] <<16); a.w  = hv[6] |(hv[7] <<16);
    b2.x = hv[8] |(hv[9] <<16); b2.y = hv[10]|(hv[11]<<16); b2.z = hv[12]|(hv[13]<<16); b2.w = hv[14]|(hv[15]<<16);
    c4.x = lv[0] |(lv[1] <<16); c4.y = lv[2] |(lv[3] <<16); c4.z = lv[4] |(lv[5] <<16); c4.w = lv[6] |(lv[7] <<16);
    d.x  = lv[8] |(lv[9] <<16); d.y  = lv[10]|(lv[11]<<16); d.z  = lv[12]|(lv[13]<<16); d.w  = lv[14]|(lv[15]<<16);
    *reinterpret_cast<uint4*>(dst +  0) = a;
    *reinterpret_cast<uint4*>(dst +  8) = b2;
    *reinterpret_cast<uint4*>(dst + 16) = c4;
    *reinterpret_cast<uint4*>(dst + 24) = d;
}

// ---------------------------------------------------------------- Msum = M[:,0]+M[:,1]
__global__ __launch_bounds__(256) void k_msum(const float* __restrict__ M, float* __restrict__ msum){
    int i = blockIdx.x*256 + threadIdx.x;
    int b = i >> 14, hw = i & (HW-1);
    msum[i] = M[(size_t)b*2*HW + hw] + M[(size_t)b*2*HW + HW + hw];
}

// ---------------------------------------------------------------- conv a/b: ZERO-LDS streaming GEMM
// Out[128][256-hw tile] = relu((W @ X + bias)*Msum); z picks wa->OutA / wb->OutB.
// W,X direct-to-register; no barriers; 2-set register pipeline.
template<int NCH, bool GX>
__global__ __launch_bounds__(512,8) void k_cab(
    const unsigned short* __restrict__ Wp,     // [2z][NCH][2][128][32]
    const unsigned short* __restrict__ Xsrc,   // [b][ht][NCH][256][32]
    const float* __restrict__ biasA, const float* __restrict__ biasB,
    const float* __restrict__ msum,
    unsigned short* __restrict__ OutA, unsigned short* __restrict__ OutB, int b0)
{
    const int bi = blockIdx.y, bg = b0 + bi;
    const int ht = blockIdx.x >> 1, z = blockIdx.x & 1;
    const int t = threadIdx.x, w = t >> 6, lane = t & 63;
    const int lr = lane & 15, lg = lane >> 4;
    const int wm = w & 1, wn = w >> 1;
    const unsigned short* Wseg  = Wp + (size_t)z*NCH*8192;
    const unsigned short* xbase = Xsrc + ((size_t)(GX ? bg : bi)*64 + ht)*(size_t)NCH*8192;

    f32x4 acc[4][4];
    #pragma unroll
    for(int mf=0;mf<4;mf++)
        #pragma unroll
        for(int nf=0;nf<4;nf++) acc[mf][nf] = (f32x4){0.f,0.f,0.f,0.f};

    bf16x8 w0[8], w1[8], x0[4], x1[4];
    auto loadW = [&](int ck, bf16x8 (&wr)[8]){
        const unsigned short* s = Wseg + (size_t)ck*8192;
        #pragma unroll
        for(int mf=0;mf<4;mf++){
            int row = wm*64 + mf*16 + lr;
            wr[mf*2+0] = *reinterpret_cast<const bf16x8*>(s + row*32 + lg*8);
            wr[mf*2+1] = *reinterpret_cast<const bf16x8*>(s + 4096 + row*32 + lg*8);
        }
    };
    auto loadX = [&](int ck, bf16x8 (&xr)[4]){
        const unsigned short* s = xbase + (size_t)ck*8192;
        #pragma unroll
        for(int nf=0;nf<4;nf++){
            int hwin = wn*64 + nf*16 + lr;
            xr[nf] = *reinterpret_cast<const bf16x8*>(s + hwin*32 + lg*8);
        }
    };
    auto compute = [&](bf16x8 (&wr)[8], bf16x8 (&xr)[4]){
        #pragma unroll
        for(int nf=0;nf<4;nf++)
            #pragma unroll
            for(int mf=0;mf<4;mf++){
                acc[mf][nf] = __builtin_amdgcn_mfma_f32_16x16x32_bf16(wr[mf*2+0], xr[nf], acc[mf][nf], 0,0,0);
                acc[mf][nf] = __builtin_amdgcn_mfma_f32_16x16x32_bf16(wr[mf*2+1], xr[nf], acc[mf][nf], 0,0,0);
            }
    };

    loadW(0, w0); loadX(0, x0);
#define CSTEP(I) \
    if constexpr ((I) < NCH){ \
        if constexpr ((I)+1 < NCH){ \
            if constexpr ((((I)+1)&1)==0){ loadW((I)+1, w0); loadX((I)+1, x0); } \
            else                         { loadW((I)+1, w1); loadX((I)+1, x1); } \
        } \
        if constexpr (((I)&1)==0) compute(w0, x0); else compute(w1, x1); \
    }
    CSTEP(0) CSTEP(1) CSTEP(2) CSTEP(3)
#undef CSTEP

    float msv[4];
    #pragma unroll
    for(int nf=0;nf<4;nf++) msv[nf] = msum[(size_t)bg*HW + ht*256 + wn*64 + nf*16 + lr];
    const float* bias = z ? biasB : biasA;
    unsigned short* dst = (z ? OutB : OutA) + (size_t)bi*CCH*HW;
    #pragma unroll
    for(int mf=0;mf<4;mf++){
        #pragma unroll
        for(int reg=0;reg<4;reg++){
            int row = wm*64 + mf*16 + lg*4 + reg;
            float bv = bias[row];
            #pragma unroll
            for(int nf=0;nf<4;nf++){
                float v2 = (acc[mf][nf][reg] + bv) * msv[nf];
                v2 = v2 > 0.f ? v2 : 0.f;
                dst[(size_t)row*HW + ht*256 + wn*64 + nf*16 + lr] = f2bf(v2);
            }
        }
    }
}

// ---------------------------------------------------------------- conv c: LDS only for P-transpose
// Out = relu((Wc @ [P*ms; X] + bc)*ms); fused diag-reduce; optional hw-major store for next block.
template<int NCHP, int NCHX, bool GX, bool STORE>
__global__ __launch_bounds__(512,8) void k_cc(
    const unsigned short* __restrict__ Wp,     // [NCH][2][128][32]
    const unsigned short* __restrict__ Psrc,   // plain [bi][128][HW], raw (no ms)
    const unsigned short* __restrict__ Xsrc,   // [b][ht][NCHX][256][32]
    const float* __restrict__ bc,
    const float* __restrict__ msum, const float* __restrict__ Mfull,
    unsigned short* __restrict__ Xout,         // [bi][ht][4][256][32]
    float* __restrict__ xo, int b0, int xo_off)
{
    constexpr int NCH = NCHP + NCHX;
    __shared__ unsigned short Pl[2*8192];      // 32 KB dbuf, XOR-swizzled
    const int bi = blockIdx.y, bg = b0 + bi, ht = blockIdx.x;
    const int t = threadIdx.x, w = t >> 6, lane = t & 63;
    const int lr = lane & 15, lg = lane >> 4;
    const int wm = w & 1, wn = w >> 1;
    const int cg = t & 7, h4 = t >> 3;
    const unsigned short* pbase = Psrc + (size_t)bi*CCH*HW + ht*256;
    const unsigned short* xbase = Xsrc + ((size_t)(GX ? bg : bi)*64 + ht)*(size_t)NCHX*8192;

    float msp[4];
    #pragma unroll
    for(int j=0;j<4;j++) msp[j] = msum[(size_t)bg*HW + ht*256 + h4*4 + j];

    f32x4 acc[4][4];
    #pragma unroll
    for(int mf=0;mf<4;mf++)
        #pragma unroll
        for(int nf=0;nf<4;nf++) acc[mf][nf] = (f32x4){0.f,0.f,0.f,0.f};

    uint2 pr0[4], pr1[4];
    bf16x8 w0[8], w1[8], x0[4], x1[4];

    auto loadP = [&](int ck, uint2 (&pr)[4]){
        const unsigned short* s = pbase + (size_t)(ck*32 + cg*4)*HW + h4*4;
        #pragma unroll
        for(int i2=0;i2<4;i2++) pr[i2] = *reinterpret_cast<const uint2*>(s + (size_t)i2*HW);
    };
    // write P*ms, transposed, XOR-swizzled (pair-granule ^ (hwin>>1)&3)
    auto writePms = [&](uint2 (&pr)[4], int buf){
        #pragma unroll
        for(int j=0;j<4;j++){
            int hwin = h4*4 + j;
            float m = msp[j];
            unsigned int a0 = f2bf(bf2f((unsigned short)h16(pr[0],j)) * m);
            unsigned int a1 = f2bf(bf2f((unsigned short)h16(pr[1],j)) * m);
            unsigned int a2 = f2bf(bf2f((unsigned short)h16(pr[2],j)) * m);
            unsigned int a3 = f2bf(bf2f((unsigned short)h16(pr[3],j)) * m);
            uint2 v; v.x = a0 | (a1 << 16); v.y = a2 | (a3 << 16);
            int pos = (((cg>>1) ^ ((hwin>>1)&3)) << 3) + (cg&1)*4;
            *reinterpret_cast<uint2*>(&Pl[buf*8192 + hwin*32 + pos]) = v;
        }
    };
    auto loadW = [&](int ck, bf16x8 (&wr)[8]){
        const unsigned short* s = Wp + (size_t)ck*8192;
        #pragma unroll
        for(int mf=0;mf<4;mf++){
            int row = wm*64 + mf*16 + lr;
            wr[mf*2+0] = *reinterpret_cast<const bf16x8*>(s + row*32 + lg*8);
            wr[mf*2+1] = *reinterpret_cast<const bf16x8*>(s + 4096 + row*32 + lg*8);
        }
    };
    auto loadX = [&](int ckAbs, bf16x8 (&xr)[4]){
        const unsigned short* s = xbase + (size_t)(ckAbs - NCHP)*8192;
        #pragma unroll
        for(int nf=0;nf<4;nf++){
            int hwin = wn*64 + nf*16 + lr;
            xr[nf] = *reinterpret_cast<const bf16x8*>(s + hwin*32 + lg*8);
        }
    };
    auto computeP = [&](bf16x8 (&wr)[8], int buf){
        #pragma unroll
        for(int nf=0;nf<4;nf++){
            int hwin = wn*64 + nf*16 + lr;
            bf16x8 bfr = *reinterpret_cast<const bf16x8*>(&Pl[buf*8192 + hwin*32 + ((lg ^ ((hwin>>1)&3)) << 3)]);
            #pragma unroll
            for(int mf=0;mf<4;mf++){
                acc[mf][nf] = __builtin_amdgcn_mfma_f32_16x16x32_bf16(wr[mf*2+0], bfr, acc[mf][nf], 0,0,0);
                acc[mf][nf] = __builtin_amdgcn_mfma_f32_16x16x32_bf16(wr[mf*2+1], bfr, acc[mf][nf], 0,0,0);
            }
        }
    };
    auto computeX = [&](bf16x8 (&wr)[8], bf16x8 (&xr)[4]){
        #pragma unroll
        for(int nf=0;nf<4;nf++)
            #pragma unroll
            for(int mf=0;mf<4;mf++){
                acc[mf][nf] = __builtin_amdgcn_mfma_f32_16x16x32_bf16(wr[mf*2+0], xr[nf], acc[mf][nf], 0,0,0);
                acc[mf][nf] = __builtin_amdgcn_mfma_f32_16x16x32_bf16(wr[mf*2+1], xr[nf], acc[mf][nf], 0,0,0);
            }
    };

    // prologue
    loadW(0, w0);
    loadP(0, pr0);
    if constexpr (NCHP > 1) loadP(1, pr1);

    // P-phase: 1 barrier/chunk, Pl dbuf
#define PSTEP(I) \
    if constexpr ((I) < NCHP){ \
        if constexpr (((I)&1)==0) writePms(pr0, 0); else writePms(pr1, 1); \
        asm volatile("s_waitcnt lgkmcnt(0)" ::: "memory"); \
        __builtin_amdgcn_sched_barrier(0); \
        __builtin_amdgcn_s_barrier(); \
        __builtin_amdgcn_sched_barrier(0); \
        if constexpr ((I)+1 < NCH){ \
            if constexpr ((((I)+1)&1)==0) loadW((I)+1, w0); else loadW((I)+1, w1); \
        } \
        if constexpr ((I)+2 < NCHP){ \
            if constexpr (((I)&1)==0) loadP((I)+2, pr0); else loadP((I)+2, pr1); \
        } \
        if constexpr (((I)+1 >= NCHP) && ((I)+1 < NCH)){ \
            if constexpr ((((I)+1)&1)==0) loadX((I)+1, x0); else loadX((I)+1, x1); \
        } \
        __builtin_amdgcn_s_setprio(1); \
        if constexpr (((I)&1)==0) computeP(w0, 0); else computeP(w1, 1); \
        __builtin_amdgcn_s_setprio(0); \
    }
    PSTEP(0) PSTEP(1) PSTEP(2) PSTEP(3)
#undef PSTEP

    // X-phase: barrier-free streaming
#define XSTEP(I) \
    if constexpr ((I) >= NCHP && (I) < NCH){ \
        if constexpr ((I)+1 < NCH){ \
            if constexpr ((((I)+1)&1)==0){ loadW((I)+1, w0); loadX((I)+1, x0); } \
            else                         { loadW((I)+1, w1); loadX((I)+1, x1); } \
        } \
        if constexpr (((I)&1)==0) computeX(w0, x0); else computeX(w1, x1); \
    }
    XSTEP(4) XSTEP(5) XSTEP(6) XSTEP(7)
#undef XSTEP

    // epilogue: bias, *ms, relu, fused diag-reduce, optional hw-major store
    float msv[4], mdv[4];
    #pragma unroll
    for(int nf=0;nf<4;nf++){
        int hwi = ht*256 + wn*64 + nf*16 + lr;
        msv[nf] = msum[(size_t)bg*HW + hwi];
        mdv[nf] = Mfull[(size_t)bg*2*HW + hwi];
    }
    #pragma unroll
    for(int mf=0;mf<4;mf++){
        const int ckO = wm*2 + (mf>>1);
        const int c0  = (mf&1)*16 + lg*4;
        float red[4] = {0.f,0.f,0.f,0.f};
        #pragma unroll
        for(int nf=0;nf<4;nf++){
            int hwin = wn*64 + nf*16 + lr;
            float vv[4];
            #pragma unroll
            for(int reg=0;reg<4;reg++){
                int row = wm*64 + mf*16 + lg*4 + reg;
                float v2 = (acc[mf][nf][reg] + bc[row]) * msv[nf];
                v2 = v2 > 0.f ? v2 : 0.f;
                vv[reg] = v2;
                red[reg] += v2 * mdv[nf];
            }
            if constexpr (STORE){
                uint2 pk;
                pk.x = (unsigned int)f2bf(vv[0]) | ((unsigned int)f2bf(vv[1]) << 16);
                pk.y = (unsigned int)f2bf(vv[2]) | ((unsigned int)f2bf(vv[3]) << 16);
                *reinterpret_cast<uint2*>(Xout + (((size_t)bi*64 + ht)*4 + ckO)*8192 + hwin*32 + c0) = pk;
            }
        }
        #pragma unroll
        for(int reg=0;reg<4;reg++){
            float r = red[reg];
            r += __shfl_xor(r, 1);
            r += __shfl_xor(r, 2);
            r += __shfl_xor(r, 4);
            r += __shfl_xor(r, 8);
            if(lr == 0)
                atomicAdd(&xo[(size_t)bg*384 + xo_off + wm*64 + mf*16 + lg*4 + reg], r);
        }
    }
}

// ---------------------------------------------------------------- batched spatial matmul:
// P[b,c] = A[b,c] @ B[b,c]  (RAW, no ms — deferred to k_cc; P aliases A)
__global__ __launch_bounds__(256) void k_bmm(
    const unsigned short* __restrict__ A, const unsigned short* __restrict__ Bm,
    unsigned short* __restrict__ P, int b0)
{
    (void)b0;
    __shared__ unsigned short Bs[128*136];
    const int m  = blockIdx.x;
    const unsigned short* Ab = A  + (size_t)m*HW;
    const unsigned short* Bb = Bm + (size_t)m*HW;
    unsigned short*       Pb = P  + (size_t)m*HW;
    const int t = threadIdx.x;
    const int w  = t >> 6;
    const int l  = t & 63;
    const int lr = l & 15;
    const int lg = l >> 4;

    bf16x8 af[4][2];
    #pragma unroll
    for(int kk=0;kk<4;kk++)
        #pragma unroll
        for(int rt=0;rt<2;rt++)
            af[kk][rt] = *reinterpret_cast<const bf16x8*>(Ab + (size_t)(w*32 + rt*16 + lr)*128 + kk*32 + lg*8);

    #pragma unroll
    for(int it=0; it<8; it++){
        int task = it*256 + t;
        int j  = task & 127;
        int kg = task >> 7;
        unsigned short v[8];
        #pragma unroll
        for(int i=0;i<8;i++) v[i] = Bb[(size_t)(kg*8+i)*128 + j];
        uint4 pk;
        pk.x = (unsigned int)v[0] | ((unsigned int)v[1]<<16);
        pk.y = (unsigned int)v[2] | ((unsigned int)v[3]<<16);
        pk.z = (unsigned int)v[4] | ((unsigned int)v[5]<<16);
        pk.w = (unsigned int)v[6] | ((unsigned int)v[7]<<16);
        *reinterpret_cast<uint4*>(&Bs[j*136 + kg*8]) = pk;
    }
    __syncthreads();

    f32x4 acc[2][8];
    #pragma unroll
    for(int rt=0;rt<2;rt++)
        #pragma unroll
        for(int ct=0;ct<8;ct++) acc[rt][ct] = (f32x4){0.f,0.f,0.f,0.f};

    #pragma unroll
    for(int kk=0;kk<4;kk++){
        #pragma unroll
        for(int ct=0;ct<8;ct++){
            bf16x8 bfr = *reinterpret_cast<const bf16x8*>(&Bs[(ct*16+lr)*136 + kk*32 + lg*8]);
            acc[0][ct] = __builtin_amdgcn_mfma_f32_16x16x32_bf16(af[kk][0], bfr, acc[0][ct], 0,0,0);
            acc[1][ct] = __builtin_amdgcn_mfma_f32_16x16x32_bf16(af[kk][1], bfr, acc[1][ct], 0,0,0);
        }
    }
    #pragma unroll
    for(int rt=0;rt<2;rt++){
        #pragma unroll
        for(int ct=0;ct<8;ct++){
            #pragma unroll
            for(int r=0;r<4;r++){
                int row = w*32 + rt*16 + lg*4 + r;
                int col = ct*16 + lr;
                Pb[(size_t)row*128 + col] = f2bf(acc[rt][ct][r]);
            }
        }
    }
}

// ---------------------------------------------------------------- head
__global__ __launch_bounds__(1024) void k_head(
    const float* __restrict__ xo, const float* __restrict__ h1w, const float* __restrict__ h1b,
    const float* __restrict__ h2w, const float* __restrict__ h2b, float* __restrict__ out)
{
    __shared__ float hbuf[NBATCH][32];
    const int t = threadIdx.x;
    const int b = t >> 5, j = t & 31;
    float a = h1b[j];
    #pragma unroll 8
    for(int k=0;k<384;k++) a += xo[b*384+k]*h1w[j*384+k];
    a = a > 0.f ? a : 0.f;
    hbuf[b][j] = a;
    __syncthreads();
    if(j == 0){
        float s = h2b[0];
        #pragma unroll
        for(int k=0;k<32;k++) s += hbuf[b][k]*h2w[k];
        out[b] = s;
    }
}

// ----------------------------------------------------------------
extern "C" void kernel_launch(void* const* d_in, const int* in_sizes, int n_in,
                              void* d_out, int out_size, void* d_ws, size_t ws_size,
                              hipStream_t stream)
{
    (void)in_sizes; (void)n_in; (void)out_size;
    const float* X2  = (const float*)d_in[0];
    const float* M   = (const float*)d_in[1];
    const float* w11 = (const float*)d_in[2];  const float* b11 = (const float*)d_in[3];
    const float* w12 = (const float*)d_in[4];  const float* b12 = (const float*)d_in[5];
    const float* w13 = (const float*)d_in[6];  const float* b13 = (const float*)d_in[7];
    const float* w21 = (const float*)d_in[8];  const float* b21 = (const float*)d_in[9];
    const float* w22 = (const float*)d_in[10]; const float* b22 = (const float*)d_in[11];
    const float* w23 = (const float*)d_in[12]; const float* b23 = (const float*)d_in[13];
    const float* w31 = (const float*)d_in[14]; const float* b31 = (const float*)d_in[15];
    const float* w32 = (const float*)d_in[16]; const float* b32 = (const float*)d_in[17];
    const float* w33 = (const float*)d_in[18]; const float* b33 = (const float*)d_in[19];
    const float* h1w = (const float*)d_in[20]; const float* h1b = (const float*)d_in[21];
    const float* h2w = (const float*)d_in[22]; const float* h2b = (const float*)d_in[23];
    float* out = (float*)d_out;

    char* ws = (char*)d_ws;
    size_t off = 0;
    float* msum = (float*)(ws + off); off += (size_t)NBATCH*HW*4;            // 2 MB
    float* xo   = (float*)(ws + off); off += (size_t)NBATCH*384*4;           // 48 KB
    unsigned short* wp  = (unsigned short*)(ws + off); off += (size_t)WPREP_TOTAL*2; // 624 KB
    off = (off + 255) & ~(size_t)255;
    unsigned short* X2b = (unsigned short*)(ws + off); off += (size_t)NBATCH*64*8192*2; // 32 MB
    off = (off + 255) & ~(size_t)255;

    int bc = 32;
    while (bc > 1 && off + 3ull*(size_t)bc*CCH*HW*2 > ws_size) bc >>= 1;
    size_t bufb = (size_t)bc*CCH*HW*2;
    unsigned short* B0 = (unsigned short*)(ws + off);
    unsigned short* B1 = (unsigned short*)(ws + off + bufb);
    unsigned short* B2 = (unsigned short*)(ws + off + 2*bufb);

    const unsigned short* Wab1 = wp + 0;
    const unsigned short* Wc1  = wp + 16384;
    const unsigned short* Wab2 = wp + 57344;
    const unsigned short* Wc2  = wp + 122880;
    const unsigned short* Wab3 = wp + 188416;
    const unsigned short* Wc3  = wp + 253952;

    k_prep<<<(WPREP_TOTAL+255)/256, 256, 0, stream>>>(w11,w12,w13,w21,w22,w23,w31,w32,w33, wp);
    k_xprep<<<dim3(64, NBATCH), 256, 0, stream>>>(X2, X2b);
    k_msum<<<(NBATCH*HW)/256, 256, 0, stream>>>(M, msum);
    hipMemsetAsync(xo, 0, (size_t)NBATCH*384*4, stream);

    for(int b0 = 0; b0 < NBATCH; b0 += bc){
        dim3 gab(128, bc);
        dim3 gcc(64, bc);
        dim3 gmat(bc*CCH);
        // ---- block 1
        k_cab<1,true ><<<gab, 512, 0, stream>>>(Wab1, X2b, b11, b12, msum, B0, B1, b0);
        k_bmm<<<gmat, 256, 0, stream>>>(B0, B1, B0, b0);
        k_cc <4,1,true ,true ><<<gcc, 512, 0, stream>>>(Wc1, B0, X2b, b13, msum, M, B1, xo, b0, 0);
        // ---- block 2 (X = B1)
        k_cab<4,false><<<gab, 512, 0, stream>>>(Wab2, B1, b21, b22, msum, B0, B2, b0);
        k_bmm<<<gmat, 256, 0, stream>>>(B0, B2, B0, b0);
        k_cc <4,4,false,true ><<<gcc, 512, 0, stream>>>(Wc2, B0, B1, b23, msum, M, B2, xo, b0, 128);
        // ---- block 3 (X = B2)
        k_cab<4,false><<<gab, 512, 0, stream>>>(Wab3, B2, b31, b32, msum, B0, B1, b0);
        k_bmm<<<gmat, 256, 0, stream>>>(B0, B1, B0, b0);
        k_cc <4,4,false,false><<<gcc, 512, 0, stream>>>(Wc3, B0, B2, b33, msum, M, nullptr, xo, b0, 256);
    }
    k_head<<<1, 1024, 0, stream>>>(xo, h1w, h1b, h2w, h2b, out);
}

// Round 10
// 1147.161 us; speedup vs baseline: 4.8497x; 4.8497x over previous
//
#include <hip/hip_runtime.h>
#include <stdint.h>
#include <stddef.h>

#define NBATCH 32
#define HW     16384      // 128*128
#define CCH    128
#define WROW   40         // padded W row stride (shorts)
#define WCHUNK 10240      // [2][128][40] shorts per K-chunk (20 KB)

typedef short bf16x8 __attribute__((ext_vector_type(8)));
typedef float f32x4  __attribute__((ext_vector_type(4)));

__device__ __forceinline__ float bf2f(unsigned short u){
    union { unsigned int i; float f; } v; v.i = ((unsigned int)u) << 16; return v.f;
}
__device__ __forceinline__ unsigned short f2bf(float f){
    union { float f; unsigned int i; } v; v.f = f;
    unsigned int x = v.i;
    x += 0x7fffu + ((x >> 16) & 1u);   // round-to-nearest-even
    return (unsigned short)(x >> 16);
}
__device__ __forceinline__ unsigned int h16(uint2 u, int j){
    unsigned int v = (j & 2) ? u.y : u.x;
    return (j & 1) ? (v >> 16) : (v & 0xffffu);
}
__device__ __forceinline__ void gl_lds16(const unsigned short* g, unsigned short* l){
    __builtin_amdgcn_global_load_lds(
        reinterpret_cast<const __attribute__((address_space(1))) unsigned int*>(
            reinterpret_cast<uintptr_t>(g)),
        reinterpret_cast<__attribute__((address_space(3))) unsigned int*>(
            reinterpret_cast<uintptr_t>(l)),
        16, 0, 0);
}
template<int N> __device__ __forceinline__ void vmwait(){
    asm volatile("s_waitcnt vmcnt(%0)" :: "n"(N) : "memory");
}

// ---------------------------------------------------------------- weight prep (R5-identical):
// per conv: [NCH][2(hi/lo)][128][40] bf16, cols 32..39 zero pad.
// segments (shorts): wa1@0 wb1@10240 wc1@20480(n5) wa2@71680(n4) wb2@112640
// wc2@153600(n8) wa3@235520 wb3@276480 wc3@317440(n8). total 399360.
#define WPREP_TOTAL 399360
__global__ __launch_bounds__(256) void k_prep(
    const float* __restrict__ w11, const float* __restrict__ w12, const float* __restrict__ w13,
    const float* __restrict__ w21, const float* __restrict__ w22, const float* __restrict__ w23,
    const float* __restrict__ w31, const float* __restrict__ w32, const float* __restrict__ w33,
    unsigned short* __restrict__ wp)
{
    int i = blockIdx.x*256 + threadIdx.x;
    if(i >= WPREP_TOTAL) return;
    const float* src; int K, mode, base;
    if     (i < 10240) { src=w11; K=16;  mode=1; base=0;      }
    else if(i < 20480) { src=w12; K=16;  mode=1; base=10240;  }
    else if(i < 71680) { src=w13; K=144; mode=2; base=20480;  }
    else if(i < 112640){ src=w21; K=128; mode=0; base=71680;  }
    else if(i < 153600){ src=w22; K=128; mode=0; base=112640; }
    else if(i < 235520){ src=w23; K=256; mode=0; base=153600; }
    else if(i < 276480){ src=w31; K=128; mode=0; base=235520; }
    else if(i < 317440){ src=w32; K=128; mode=0; base=276480; }
    else               { src=w33; K=256; mode=0; base=317440; }
    int j  = i - base;
    int ck = j / WCHUNK;
    int jj = j - ck*WCHUNK;
    int half = jj / 5120;
    int rr   = (jj / WROW) & 127;
    int c    = jj % WROW;
    float v = 0.f;
    if(c < 32){
        int col = (mode==1) ? (c & 15)
                : (mode==2) ? (ck < 4 ? ck*32 + c : 128 + (c & 15))
                :             ck*32 + c;
        v = src[rr*K + col];
    }
    unsigned short hi = f2bf(v);
    wp[i] = half ? f2bf(v - bf2f(hi)) : hi;
}

// ---------------------------------------------------------------- Msum = M[:,0]+M[:,1]
__global__ __launch_bounds__(256) void k_msum(const float* __restrict__ M, float* __restrict__ msum){
    int i = blockIdx.x*256 + threadIdx.x;
    int b = i >> 14, hw = i & (HW-1);
    msum[i] = M[(size_t)b*2*HW + hw] + M[(size_t)b*2*HW + HW + hw];
}

// ---------------------------------------------------------------- unified conv GEMM (256 thr, 4 waves 2x2)
// Out[128][256-hw] = relu((W @ concat(P,X) + bias)*Msum). KC=32 (x2 hi/lo MFMA).
// NEW vs R5: Xt dbuf -> ONE barrier/chunk; X/P reg prefetch depth-2; counted vmcnt (never 0 in loop);
// setprio around MFMA cluster; STORE=false skips dead cc3 output.
template<int NCHP, int NCHX, bool CC, bool XS, bool STORE>
__global__ __launch_bounds__(256,2) void k_conv(
    const unsigned short* __restrict__ Wp,
    const unsigned short* __restrict__ Psrc,   // plain [bi][128][HW]
    const void* __restrict__ Xsrc,             // XS: f32 [bg][16][HW]; else bf16 [bi][128][HW]
    const float* __restrict__ biasA, const float* __restrict__ biasB,
    const float* __restrict__ msum, const float* __restrict__ Mfull,
    unsigned short* __restrict__ OutA, unsigned short* __restrict__ OutB,
    float* __restrict__ xo, int b0, int xo_off)
{
    constexpr int NCH = NCHP + NCHX;
    __shared__ unsigned short Wl[2*WCHUNK];    // 40 KB double-buffered W
    __shared__ unsigned short Xt[2*10240];     // 40 KB double-buffered X^T
    const int bi = blockIdx.y, bg = b0 + bi;
    const int hw0 = blockIdx.x * 256;
    const int z = CC ? 0 : blockIdx.z;
    const int t = threadIdx.x;
    const int w = t >> 6, l = t & 63;
    const int lr = l & 15, lg = l >> 4;
    const int wm = w & 1, wn = w >> 1;           // rows wm*64.., cols wn*128..
    const int cg = t & 3, h4 = t >> 2;           // X staging mapping
    const unsigned short* Wseg  = Wp + (size_t)z*NCH*WCHUNK;
    const unsigned short* pbase = Psrc + (size_t)bi*CCH*HW;
    const float* xfbase = nullptr;
    const unsigned short* xbbase = nullptr;
    if constexpr (XS) xfbase = (const float*)Xsrc + (size_t)bg*16*HW;
    else              xbbase = (const unsigned short*)Xsrc + (size_t)bi*CCH*HW;

    f32x4 acc[4][8];
    #pragma unroll
    for(int mf=0; mf<4; mf++)
        #pragma unroll
        for(int nf=0; nf<8; nf++) acc[mf][nf] = (f32x4){0.f,0.f,0.f,0.f};

    uint2 xr0[8], xr1[8];
    float xf0[16], xf1[16];

    auto wdma = [&](int ck){
        const unsigned short* s = Wseg + (size_t)ck*WCHUNK + (size_t)t*8;
        unsigned short* d = &Wl[(ck & 1)*WCHUNK + t*8];
        #pragma unroll
        for(int r=0; r<5; r++)
            gl_lds16(s + (size_t)r*2048, d + r*2048);
    };
    auto loadXb = [&](int ck, uint2 (&xr)[8]){
        const unsigned short* s = ((ck < NCHP) ? (pbase + (size_t)ck*32*HW)
                                               : (xbbase + (size_t)(ck-NCHP)*32*HW))
                                  + hw0 + h4*4;
        #pragma unroll
        for(int i=0;i<8;i++) xr[i] = *reinterpret_cast<const uint2*>(s + (size_t)(cg*8+i)*HW);
    };
    auto loadXf = [&](float (&xf)[16]){
        const float* s = xfbase + hw0 + t;
        #pragma unroll
        for(int c=0;c<16;c++) xf[c] = s[(size_t)c*HW];
    };
    auto writeXb = [&](int buf, uint2 (&xr)[8]){
        #pragma unroll
        for(int j=0;j<4;j++){
            uint4 pk;
            pk.x = h16(xr[0],j) | (h16(xr[1],j) << 16);
            pk.y = h16(xr[2],j) | (h16(xr[3],j) << 16);
            pk.z = h16(xr[4],j) | (h16(xr[5],j) << 16);
            pk.w = h16(xr[6],j) | (h16(xr[7],j) << 16);
            *reinterpret_cast<uint4*>(&Xt[buf*10240 + (h4*4+j)*WROW + cg*8]) = pk;
        }
    };
    auto writeXf = [&](int buf, float (&xf)[16]){
        unsigned int hi[16], lo[16];
        #pragma unroll
        for(int c=0;c<16;c++){
            unsigned short h = f2bf(xf[c]);
            hi[c] = h;
            lo[c] = f2bf(xf[c] - bf2f(h));
        }
        uint4 a, b2, c4, d;
        a.x  = hi[0] |(hi[1] <<16); a.y  = hi[2] |(hi[3] <<16); a.z  = hi[4] |(hi[5] <<16); a.w  = hi[6] |(hi[7] <<16);
        b2.x = hi[8] |(hi[9] <<16); b2.y = hi[10]|(hi[11]<<16); b2.z = hi[12]|(hi[13]<<16); b2.w = hi[14]|(hi[15]<<16);
        c4.x = lo[0] |(lo[1] <<16); c4.y = lo[2] |(lo[3] <<16); c4.z = lo[4] |(lo[5] <<16); c4.w = lo[6] |(lo[7] <<16);
        d.x  = lo[8] |(lo[9] <<16); d.y  = lo[10]|(lo[11]<<16); d.z  = lo[12]|(lo[13]<<16); d.w  = lo[14]|(lo[15]<<16);
        unsigned short* base = &Xt[buf*10240 + t*WROW];
        *reinterpret_cast<uint4*>(base +  0) = a;
        *reinterpret_cast<uint4*>(base +  8) = b2;
        *reinterpret_cast<uint4*>(base + 16) = c4;
        *reinterpret_cast<uint4*>(base + 24) = d;
    };
    auto compute = [&](int buf){
        const unsigned short* Wb = &Wl[buf*WCHUNK];
        const unsigned short* Xb = &Xt[buf*10240];
        bf16x8 ah[4], al[4];
        #pragma unroll
        for(int mf=0; mf<4; mf++){
            ah[mf] = *reinterpret_cast<const bf16x8*>(&Wb[(wm*64 + mf*16 + lr)*WROW + lg*8]);
            al[mf] = *reinterpret_cast<const bf16x8*>(&Wb[(128 + wm*64 + mf*16 + lr)*WROW + lg*8]);
        }
        #pragma unroll
        for(int nf=0; nf<8; nf++){
            bf16x8 bfr = *reinterpret_cast<const bf16x8*>(&Xb[(wn*128 + nf*16 + lr)*WROW + lg*8]);
            #pragma unroll
            for(int mf=0; mf<4; mf++){
                acc[mf][nf] = __builtin_amdgcn_mfma_f32_16x16x32_bf16(ah[mf], bfr, acc[mf][nf], 0,0,0);
                acc[mf][nf] = __builtin_amdgcn_mfma_f32_16x16x32_bf16(al[mf], bfr, acc[mf][nf], 0,0,0);
            }
        }
    };

// chunk CK is P-type (reg uint2) if CK<NCHP, else X-type (XS: 16 f32 scalar, else uint2).
#define LOADC(CK, S) \
    if constexpr ((CK) < NCHP || !XS){ \
        if constexpr ((S)==0) loadXb((CK), xr0); else loadXb((CK), xr1); \
    } else { \
        if constexpr ((S)==0) loadXf(xf0); else loadXf(xf1); \
    }

    // prologue, issue order: loadX(0) [oldest], wdma(0), loadX(1) [kept at step 0]
    LOADC(0, 0)
    __builtin_amdgcn_sched_barrier(0);
    wdma(0);
    __builtin_amdgcn_sched_barrier(0);
    if constexpr (NCH > 1){ LOADC(1, 1) }
    __builtin_amdgcn_sched_barrier(0);

    // per step I: in-flight oldest-first = loadX(I), wdma(I), loadX(I+1).
    // vmwait keeps only loadX(I+1): N = ops(I+1) (P/Xb bundle=8, XS bundle=16).
#define STEP(I) \
    if constexpr ((I) < NCH){ \
        vmwait<(((I)+1 < NCH) ? ((((I)+1) < NCHP) ? 8 : (XS ? 16 : 8)) : 0)>(); \
        __builtin_amdgcn_sched_barrier(0); \
        if constexpr ((I) < NCHP || !XS){ \
            if constexpr (((I)&1)==0) writeXb((I)&1, xr0); else writeXb((I)&1, xr1); \
        } else { \
            if constexpr (((I)&1)==0) writeXf((I)&1, xf0); else writeXf((I)&1, xf1); \
        } \
        asm volatile("s_waitcnt lgkmcnt(0)" ::: "memory"); \
        __builtin_amdgcn_sched_barrier(0); \
        __builtin_amdgcn_s_barrier(); \
        if constexpr ((I)+1 < NCH) wdma((I)+1); \
        __builtin_amdgcn_sched_barrier(0); \
        if constexpr ((I)+2 < NCH){ LOADC((I)+2, (I)&1) } \
        __builtin_amdgcn_sched_barrier(0); \
        __builtin_amdgcn_s_setprio(1); \
        compute((I)&1); \
        __builtin_amdgcn_s_setprio(0); \
    }
    STEP(0) STEP(1) STEP(2) STEP(3) STEP(4) STEP(5) STEP(6) STEP(7)
#undef STEP
#undef LOADC

    // ---- epilogue (R5-identical, + STORE guard)
    float msv[8], mdv[8];
    #pragma unroll
    for(int nf=0; nf<8; nf++){
        int hwi = hw0 + wn*128 + nf*16 + lr;
        msv[nf] = msum[(size_t)bg*HW + hwi];
        if constexpr (CC) mdv[nf] = Mfull[(size_t)bg*2*HW + hwi];
    }
    if constexpr (!CC){
        const float* bias = z ? biasB : biasA;
        unsigned short* dst = (z ? OutB : OutA) + (size_t)bi*CCH*HW;
        #pragma unroll
        for(int mf=0; mf<4; mf++){
            #pragma unroll
            for(int reg=0; reg<4; reg++){
                int row = wm*64 + mf*16 + lg*4 + reg;
                float bv = bias[row];
                #pragma unroll
                for(int nf=0; nf<8; nf++){
                    float v2 = (acc[mf][nf][reg] + bv) * msv[nf];
                    v2 = v2 > 0.f ? v2 : 0.f;
                    dst[(size_t)row*HW + hw0 + wn*128 + nf*16 + lr] = f2bf(v2);
                }
            }
        }
    } else {
        unsigned short* dst = OutA + (size_t)bi*CCH*HW;
        #pragma unroll
        for(int mf=0; mf<4; mf++){
            float red[4] = {0.f,0.f,0.f,0.f};
            #pragma unroll
            for(int reg=0; reg<4; reg++){
                int row = wm*64 + mf*16 + lg*4 + reg;
                float bv = biasA[row];
                #pragma unroll
                for(int nf=0; nf<8; nf++){
                    float v2 = (acc[mf][nf][reg] + bv) * msv[nf];
                    v2 = v2 > 0.f ? v2 : 0.f;
                    if constexpr (STORE)
                        dst[(size_t)row*HW + hw0 + wn*128 + nf*16 + lr] = f2bf(v2);
                    red[reg] += v2 * mdv[nf];
                }
            }
            #pragma unroll
            for(int reg=0; reg<4; reg++){
                float r = red[reg];
                r += __shfl_xor(r, 1);
                r += __shfl_xor(r, 2);
                r += __shfl_xor(r, 4);
                r += __shfl_xor(r, 8);
                if(lr == 0)
                    atomicAdd(&xo[(size_t)bg*384 + xo_off + wm*64 + mf*16 + lg*4 + reg], r);
            }
        }
    }
}

// ---------------------------------------------------------------- batched spatial matmul (R5-identical):
// P[b,c] = (A[b,c] @ B[b,c]) * Msum[b]  (128x128x128 bf16 MFMA; P aliases A)
__global__ __launch_bounds__(256) void k_bmm(
    const unsigned short* __restrict__ A, const unsigned short* __restrict__ Bm,
    const float* __restrict__ msum, unsigned short* __restrict__ P, int b0)
{
    __shared__ unsigned short Bs[128*136];
    const int m  = blockIdx.x;
    const int bi = m >> 7;
    const int bg = b0 + bi;
    const unsigned short* Ab = A  + (size_t)m*HW;
    const unsigned short* Bb = Bm + (size_t)m*HW;
    unsigned short*       Pb = P  + (size_t)m*HW;
    const float* ms = msum + (size_t)bg*HW;
    const int t = threadIdx.x;
    const int w  = t >> 6;
    const int l  = t & 63;
    const int lr = l & 15;
    const int lg = l >> 4;

    bf16x8 af[4][2];
    #pragma unroll
    for(int kk=0;kk<4;kk++)
        #pragma unroll
        for(int rt=0;rt<2;rt++)
            af[kk][rt] = *reinterpret_cast<const bf16x8*>(Ab + (size_t)(w*32 + rt*16 + lr)*128 + kk*32 + lg*8);

    #pragma unroll
    for(int it=0; it<8; it++){
        int task = it*256 + t;
        int j  = task & 127;
        int kg = task >> 7;
        unsigned short v[8];
        #pragma unroll
        for(int i=0;i<8;i++) v[i] = Bb[(size_t)(kg*8+i)*128 + j];
        uint4 pk;
        pk.x = (unsigned int)v[0] | ((unsigned int)v[1]<<16);
        pk.y = (unsigned int)v[2] | ((unsigned int)v[3]<<16);
        pk.z = (unsigned int)v[4] | ((unsigned int)v[5]<<16);
        pk.w = (unsigned int)v[6] | ((unsigned int)v[7]<<16);
        *reinterpret_cast<uint4*>(&Bs[j*136 + kg*8]) = pk;
    }
    __syncthreads();

    f32x4 acc[2][8];
    #pragma unroll
    for(int rt=0;rt<2;rt++)
        #pragma unroll
        for(int ct=0;ct<8;ct++) acc[rt][ct] = (f32x4){0.f,0.f,0.f,0.f};

    #pragma unroll
    for(int kk=0;kk<4;kk++){
        #pragma unroll
        for(int ct=0;ct<8;ct++){
            bf16x8 bfr = *reinterpret_cast<const bf16x8*>(&Bs[(ct*16+lr)*136 + kk*32 + lg*8]);
            acc[0][ct] = __builtin_amdgcn_mfma_f32_16x16x32_bf16(af[kk][0], bfr, acc[0][ct], 0,0,0);
            acc[1][ct] = __builtin_amdgcn_mfma_f32_16x16x32_bf16(af[kk][1], bfr, acc[1][ct], 0,0,0);
        }
    }
    #pragma unroll
    for(int rt=0;rt<2;rt++){
        #pragma unroll
        for(int ct=0;ct<8;ct++){
            #pragma unroll
            for(int r=0;r<4;r++){
                int row = w*32 + rt*16 + lg*4 + r;
                int col = ct*16 + lr;
                float v = acc[rt][ct][r] * ms[row*128 + col];
                Pb[(size_t)row*128 + col] = f2bf(v);
            }
        }
    }
}

// ---------------------------------------------------------------- head
__global__ __launch_bounds__(1024) void k_head(
    const float* __restrict__ xo, const float* __restrict__ h1w, const float* __restrict__ h1b,
    const float* __restrict__ h2w, const float* __restrict__ h2b, float* __restrict__ out)
{
    __shared__ float hbuf[NBATCH][32];
    const int t = threadIdx.x;
    const int b = t >> 5, j = t & 31;
    float a = h1b[j];
    #pragma unroll 8
    for(int k=0;k<384;k++) a += xo[b*384+k]*h1w[j*384+k];
    a = a > 0.f ? a : 0.f;
    hbuf[b][j] = a;
    __syncthreads();
    if(j == 0){
        float s = h2b[0];
        #pragma unroll
        for(int k=0;k<32;k++) s += hbuf[b][k]*h2w[k];
        out[b] = s;
    }
}

// ----------------------------------------------------------------
extern "C" void kernel_launch(void* const* d_in, const int* in_sizes, int n_in,
                              void* d_out, int out_size, void* d_ws, size_t ws_size,
                              hipStream_t stream)
{
    (void)in_sizes; (void)n_in; (void)out_size;
    const float* X2  = (const float*)d_in[0];
    const float* M   = (const float*)d_in[1];
    const float* w11 = (const float*)d_in[2];  const float* b11 = (const float*)d_in[3];
    const float* w12 = (const float*)d_in[4];  const float* b12 = (const float*)d_in[5];
    const float* w13 = (const float*)d_in[6];  const float* b13 = (const float*)d_in[7];
    const float* w21 = (const float*)d_in[8];  const float* b21 = (const float*)d_in[9];
    const float* w22 = (const float*)d_in[10]; const float* b22 = (const float*)d_in[11];
    const float* w23 = (const float*)d_in[12]; const float* b23 = (const float*)d_in[13];
    const float* w31 = (const float*)d_in[14]; const float* b31 = (const float*)d_in[15];
    const float* w32 = (const float*)d_in[16]; const float* b32 = (const float*)d_in[17];
    const float* w33 = (const float*)d_in[18]; const float* b33 = (const float*)d_in[19];
    const float* h1w = (const float*)d_in[20]; const float* h1b = (const float*)d_in[21];
    const float* h2w = (const float*)d_in[22]; const float* h2b = (const float*)d_in[23];
    float* out = (float*)d_out;

    char* ws = (char*)d_ws;
    size_t off = 0;
    float* msum = (float*)(ws + off); off += (size_t)NBATCH*HW*4;            // 2 MB
    float* xo   = (float*)(ws + off); off += (size_t)NBATCH*384*4;           // 48 KB
    unsigned short* wp = (unsigned short*)(ws + off); off += (size_t)WPREP_TOTAL*2;  // 780 KB
    off = (off + 255) & ~(size_t)255;

    int bc = 32;
    while (bc > 1 && off + 3ull*(size_t)bc*CCH*HW*2 > ws_size) bc >>= 1;
    size_t bufb = (size_t)bc*CCH*HW*2;
    unsigned short* B0 = (unsigned short*)(ws + off);
    unsigned short* B1 = (unsigned short*)(ws + off + bufb);
    unsigned short* B2 = (unsigned short*)(ws + off + 2*bufb);

    const unsigned short* Wa1 = wp + 0;        // z=1 -> +10240 = wb1
    const unsigned short* Wc1 = wp + 20480;
    const unsigned short* Wa2 = wp + 71680;    // z=1 -> +40960 = wb2
    const unsigned short* Wc2 = wp + 153600;
    const unsigned short* Wa3 = wp + 235520;   // z=1 -> +40960 = wb3
    const unsigned short* Wc3 = wp + 317440;

    k_prep<<<(WPREP_TOTAL+255)/256, 256, 0, stream>>>(w11,w12,w13,w21,w22,w23,w31,w32,w33, wp);
    k_msum<<<(NBATCH*HW)/256, 256, 0, stream>>>(M, msum);
    hipMemsetAsync(xo, 0, (size_t)NBATCH*384*4, stream);

    for(int b0 = 0; b0 < NBATCH; b0 += bc){
        dim3 gab(HW/256, bc, 2);
        dim3 gcc(HW/256, bc);
        dim3 gmat(bc*CCH);
        // ---- block 1 (X from fp32 X2, in-kernel hi/lo split)
        k_conv<0,1,false,true ,true ><<<gab, 256, 0, stream>>>(Wa1, B0, X2, b11, b12, msum, M, B0, B1, nullptr, b0, 0);
        k_bmm<<<gmat, 256, 0, stream>>>(B0, B1, msum, B0, b0);
        k_conv<4,1,true ,true ,true ><<<gcc, 256, 0, stream>>>(Wc1, B0, X2, b13, b13, msum, M, B1, nullptr, xo, b0, 0);
        // ---- block 2 (X = B1)
        k_conv<0,4,false,false,true ><<<gab, 256, 0, stream>>>(Wa2, B0, B1, b21, b22, msum, M, B2, B0, nullptr, b0, 0);
        k_bmm<<<gmat, 256, 0, stream>>>(B2, B0, msum, B2, b0);
        k_conv<4,4,true ,false,true ><<<gcc, 256, 0, stream>>>(Wc2, B2, B1, b23, b23, msum, M, B0, nullptr, xo, b0, 128);
        // ---- block 3 (X = B0)
        k_conv<0,4,false,false,true ><<<gab, 256, 0, stream>>>(Wa3, B2, B0, b31, b32, msum, M, B1, B2, nullptr, b0, 0);
        k_bmm<<<gmat, 256, 0, stream>>>(B1, B2, msum, B1, b0);
        k_conv<4,4,true ,false,false><<<gcc, 256, 0, stream>>>(Wc3, B1, B0, b33, b33, msum, M, B2, nullptr, xo, b0, 256);
    }
    k_head<<<1, 1024, 0, stream>>>(xo, h1w, h1b, h2w, h2b, out);
}

// Round 13
// 1141.411 us; speedup vs baseline: 4.8742x; 1.0050x over previous
//
#include <hip/hip_runtime.h>
#include <stdint.h>
#include <stddef.h>

#define NBATCH 32
#define HW     16384      // 128*128
#define CCH    128
#define WROW   40         // padded W row stride (shorts)
#define WCHUNK 10240      // [2][128][40] shorts per K-chunk (20 KB)

typedef short bf16x8 __attribute__((ext_vector_type(8)));
typedef float f32x4  __attribute__((ext_vector_type(4)));

__device__ __forceinline__ float bf2f(unsigned short u){
    union { unsigned int i; float f; } v; v.i = ((unsigned int)u) << 16; return v.f;
}
__device__ __forceinline__ unsigned short f2bf(float f){
    union { float f; unsigned int i; } v; v.f = f;
    unsigned int x = v.i;
    x += 0x7fffu + ((x >> 16) & 1u);   // round-to-nearest-even
    return (unsigned short)(x >> 16);
}
__device__ __forceinline__ unsigned int h16(uint2 u, int j){
    unsigned int v = (j & 2) ? u.y : u.x;
    return (j & 1) ? (v >> 16) : (v & 0xffffu);
}
__device__ __forceinline__ void gl_lds16(const unsigned short* g, unsigned short* l){
    __builtin_amdgcn_global_load_lds(
        reinterpret_cast<const __attribute__((address_space(1))) unsigned int*>(
            reinterpret_cast<uintptr_t>(g)),
        reinterpret_cast<__attribute__((address_space(3))) unsigned int*>(
            reinterpret_cast<uintptr_t>(l)),
        16, 0, 0);
}
template<int N> __device__ __forceinline__ void vmwait(){
    asm volatile("s_waitcnt vmcnt(%0)" :: "n"(N) : "memory");
}

// ---------------------------------------------------------------- fused setup:
// weight prep (hi/lo split, [NCH][2][128][40]) + msum + xo zero, one kernel.
// W segments (shorts): wa1@0 wb1@10240 wc1@20480(n5) wa2@71680(n4) wb2@112640
// wc2@153600(n8) wa3@235520 wb3@276480 wc3@317440(n8). total 399360.
#define WPREP_TOTAL 399360
__global__ __launch_bounds__(256) void k_setup(
    const float* __restrict__ w11, const float* __restrict__ w12, const float* __restrict__ w13,
    const float* __restrict__ w21, const float* __restrict__ w22, const float* __restrict__ w23,
    const float* __restrict__ w31, const float* __restrict__ w32, const float* __restrict__ w33,
    const float* __restrict__ M,
    unsigned short* __restrict__ wp, float* __restrict__ msum, float* __restrict__ xo)
{
    int i = blockIdx.x*256 + threadIdx.x;     // grid covers NBATCH*HW = 524288
    // ---- msum
    {
        int b = i >> 14, hw = i & (HW-1);
        msum[i] = M[(size_t)b*2*HW + hw] + M[(size_t)b*2*HW + HW + hw];
    }
    // ---- xo zero
    if(i < NBATCH*384) xo[i] = 0.f;
    // ---- weight prep
    if(i < WPREP_TOTAL){
        const float* src; int K, mode, base;
        if     (i < 10240) { src=w11; K=16;  mode=1; base=0;      }
        else if(i < 20480) { src=w12; K=16;  mode=1; base=10240;  }
        else if(i < 71680) { src=w13; K=144; mode=2; base=20480;  }
        else if(i < 112640){ src=w21; K=128; mode=0; base=71680;  }
        else if(i < 153600){ src=w22; K=128; mode=0; base=112640; }
        else if(i < 235520){ src=w23; K=256; mode=0; base=153600; }
        else if(i < 276480){ src=w31; K=128; mode=0; base=235520; }
        else if(i < 317440){ src=w32; K=128; mode=0; base=276480; }
        else               { src=w33; K=256; mode=0; base=317440; }
        int j  = i - base;
        int ck = j / WCHUNK;
        int jj = j - ck*WCHUNK;
        int half = jj / 5120;
        int rr   = (jj / WROW) & 127;
        int c    = jj % WROW;
        float v = 0.f;
        if(c < 32){
            int col = (mode==1) ? (c & 15)
                    : (mode==2) ? (ck < 4 ? ck*32 + c : 128 + (c & 15))
                    :             ck*32 + c;
            v = src[rr*K + col];
        }
        unsigned short hi = f2bf(v);
        wp[i] = half ? f2bf(v - bf2f(hi)) : hi;
    }
}

// ---------------------------------------------------------------- unified conv GEMM (256 thr, 4 waves 2x2)
// Out[128][256-hw] = relu((W @ concat(P,X) + bias)*Msum). KC=32 (x2 hi/lo MFMA).
// Xt dbuf -> ONE barrier/chunk; X/P reg prefetch depth-2; counted vmcnt (never 0 in loop);
// setprio around MFMA cluster; STORE=false skips dead cc3 output.
template<int NCHP, int NCHX, bool CC, bool XS, bool STORE>
__global__ __launch_bounds__(256,2) void k_conv(
    const unsigned short* __restrict__ Wp,
    const unsigned short* __restrict__ Psrc,   // plain [bi][128][HW]
    const void* __restrict__ Xsrc,             // XS: f32 [bg][16][HW]; else bf16 [bi][128][HW]
    const float* __restrict__ biasA, const float* __restrict__ biasB,
    const float* __restrict__ msum, const float* __restrict__ Mfull,
    unsigned short* __restrict__ OutA, unsigned short* __restrict__ OutB,
    float* __restrict__ xo, int b0, int xo_off)
{
    constexpr int NCH = NCHP + NCHX;
    __shared__ unsigned short Wl[2*WCHUNK];    // 40 KB double-buffered W
    __shared__ unsigned short Xt[2*10240];     // 40 KB double-buffered X^T
    const int bi = blockIdx.y, bg = b0 + bi;
    const int hw0 = blockIdx.x * 256;
    const int z = CC ? 0 : blockIdx.z;
    const int t = threadIdx.x;
    const int w = t >> 6, l = t & 63;
    const int lr = l & 15, lg = l >> 4;
    const int wm = w & 1, wn = w >> 1;           // rows wm*64.., cols wn*128..
    const int cg = t & 3, h4 = t >> 2;           // X staging mapping
    const unsigned short* Wseg  = Wp + (size_t)z*NCH*WCHUNK;
    const unsigned short* pbase = Psrc + (size_t)bi*CCH*HW;
    const float* xfbase = nullptr;
    const unsigned short* xbbase = nullptr;
    if constexpr (XS) xfbase = (const float*)Xsrc + (size_t)bg*16*HW;
    else              xbbase = (const unsigned short*)Xsrc + (size_t)bi*CCH*HW;

    f32x4 acc[4][8];
    #pragma unroll
    for(int mf=0; mf<4; mf++)
        #pragma unroll
        for(int nf=0; nf<8; nf++) acc[mf][nf] = (f32x4){0.f,0.f,0.f,0.f};

    uint2 xr0[8], xr1[8];
    float xf0[16], xf1[16];

    auto wdma = [&](int ck){
        const unsigned short* s = Wseg + (size_t)ck*WCHUNK + (size_t)t*8;
        unsigned short* d = &Wl[(ck & 1)*WCHUNK + t*8];
        #pragma unroll
        for(int r=0; r<5; r++)
            gl_lds16(s + (size_t)r*2048, d + r*2048);
    };
    auto loadXb = [&](int ck, uint2 (&xr)[8]){
        const unsigned short* s = ((ck < NCHP) ? (pbase + (size_t)ck*32*HW)
                                               : (xbbase + (size_t)(ck-NCHP)*32*HW))
                                  + hw0 + h4*4;
        #pragma unroll
        for(int i=0;i<8;i++) xr[i] = *reinterpret_cast<const uint2*>(s + (size_t)(cg*8+i)*HW);
    };
    auto loadXf = [&](float (&xf)[16]){
        const float* s = xfbase + hw0 + t;
        #pragma unroll
        for(int c=0;c<16;c++) xf[c] = s[(size_t)c*HW];
    };
    auto writeXb = [&](int buf, uint2 (&xr)[8]){
        #pragma unroll
        for(int j=0;j<4;j++){
            uint4 pk;
            pk.x = h16(xr[0],j) | (h16(xr[1],j) << 16);
            pk.y = h16(xr[2],j) | (h16(xr[3],j) << 16);
            pk.z = h16(xr[4],j) | (h16(xr[5],j) << 16);
            pk.w = h16(xr[6],j) | (h16(xr[7],j) << 16);
            *reinterpret_cast<uint4*>(&Xt[buf*10240 + (h4*4+j)*WROW + cg*8]) = pk;
        }
    };
    auto writeXf = [&](int buf, float (&xf)[16]){
        unsigned int hi[16], lo[16];
        #pragma unroll
        for(int c=0;c<16;c++){
            unsigned short h = f2bf(xf[c]);
            hi[c] = h;
            lo[c] = f2bf(xf[c] - bf2f(h));
        }
        uint4 a, b2, c4, d;
        a.x  = hi[0] |(hi[1] <<16); a.y  = hi[2] |(hi[3] <<16); a.z  = hi[4] |(hi[5] <<16); a.w  = hi[6] |(hi[7] <<16);
        b2.x = hi[8] |(hi[9] <<16); b2.y = hi[10]|(hi[11]<<16); b2.z = hi[12]|(hi[13]<<16); b2.w = hi[14]|(hi[15]<<16);
        c4.x = lo[0] |(lo[1] <<16); c4.y = lo[2] |(lo[3] <<16); c4.z = lo[4] |(lo[5] <<16); c4.w = lo[6] |(lo[7] <<16);
        d.x  = lo[8] |(lo[9] <<16); d.y  = lo[10]|(lo[11]<<16); d.z  = lo[12]|(lo[13]<<16); d.w  = lo[14]|(lo[15]<<16);
        unsigned short* base = &Xt[buf*10240 + t*WROW];
        *reinterpret_cast<uint4*>(base +  0) = a;
        *reinterpret_cast<uint4*>(base +  8) = b2;
        *reinterpret_cast<uint4*>(base + 16) = c4;
        *reinterpret_cast<uint4*>(base + 24) = d;
    };
    auto compute = [&](int buf){
        const unsigned short* Wb = &Wl[buf*WCHUNK];
        const unsigned short* Xb = &Xt[buf*10240];
        bf16x8 ah[4], al[4];
        #pragma unroll
        for(int mf=0; mf<4; mf++){
            ah[mf] = *reinterpret_cast<const bf16x8*>(&Wb[(wm*64 + mf*16 + lr)*WROW + lg*8]);
            al[mf] = *reinterpret_cast<const bf16x8*>(&Wb[(128 + wm*64 + mf*16 + lr)*WROW + lg*8]);
        }
        #pragma unroll
        for(int nf=0; nf<8; nf++){
            bf16x8 bfr = *reinterpret_cast<const bf16x8*>(&Xb[(wn*128 + nf*16 + lr)*WROW + lg*8]);
            #pragma unroll
            for(int mf=0; mf<4; mf++){
                acc[mf][nf] = __builtin_amdgcn_mfma_f32_16x16x32_bf16(ah[mf], bfr, acc[mf][nf], 0,0,0);
                acc[mf][nf] = __builtin_amdgcn_mfma_f32_16x16x32_bf16(al[mf], bfr, acc[mf][nf], 0,0,0);
            }
        }
    };

// chunk CK is P-type (reg uint2) if CK<NCHP, else X-type (XS: 16 f32 scalar, else uint2).
#define LOADC(CK, S) \
    if constexpr ((CK) < NCHP || !XS){ \
        if constexpr ((S)==0) loadXb((CK), xr0); else loadXb((CK), xr1); \
    } else { \
        if constexpr ((S)==0) loadXf(xf0); else loadXf(xf1); \
    }

    // prologue, issue order: loadX(0) [oldest], wdma(0), loadX(1) [kept at step 0]
    LOADC(0, 0)
    __builtin_amdgcn_sched_barrier(0);
    wdma(0);
    __builtin_amdgcn_sched_barrier(0);
    if constexpr (NCH > 1){ LOADC(1, 1) }
    __builtin_amdgcn_sched_barrier(0);

    // per step I: in-flight oldest-first = loadX(I), wdma(I), loadX(I+1).
    // vmwait keeps only loadX(I+1): N = ops(I+1) (P/Xb bundle=8, XS bundle=16).
#define STEP(I) \
    if constexpr ((I) < NCH){ \
        vmwait<(((I)+1 < NCH) ? ((((I)+1) < NCHP) ? 8 : (XS ? 16 : 8)) : 0)>(); \
        __builtin_amdgcn_sched_barrier(0); \
        if constexpr ((I) < NCHP || !XS){ \
            if constexpr (((I)&1)==0) writeXb((I)&1, xr0); else writeXb((I)&1, xr1); \
        } else { \
            if constexpr (((I)&1)==0) writeXf((I)&1, xf0); else writeXf((I)&1, xf1); \
        } \
        asm volatile("s_waitcnt lgkmcnt(0)" ::: "memory"); \
        __builtin_amdgcn_sched_barrier(0); \
        __builtin_amdgcn_s_barrier(); \
        if constexpr ((I)+1 < NCH) wdma((I)+1); \
        __builtin_amdgcn_sched_barrier(0); \
        if constexpr ((I)+2 < NCH){ LOADC((I)+2, (I)&1) } \
        __builtin_amdgcn_sched_barrier(0); \
        __builtin_amdgcn_s_setprio(1); \
        compute((I)&1); \
        __builtin_amdgcn_s_setprio(0); \
    }
    STEP(0) STEP(1) STEP(2) STEP(3) STEP(4) STEP(5) STEP(6) STEP(7)
#undef STEP
#undef LOADC

    // ---- epilogue
    float msv[8], mdv[8];
    #pragma unroll
    for(int nf=0; nf<8; nf++){
        int hwi = hw0 + wn*128 + nf*16 + lr;
        msv[nf] = msum[(size_t)bg*HW + hwi];
        if constexpr (CC) mdv[nf] = Mfull[(size_t)bg*2*HW + hwi];
    }
    if constexpr (!CC){
        const float* bias = z ? biasB : biasA;
        unsigned short* dst = (z ? OutB : OutA) + (size_t)bi*CCH*HW;
        #pragma unroll
        for(int mf=0; mf<4; mf++){
            #pragma unroll
            for(int reg=0; reg<4; reg++){
                int row = wm*64 + mf*16 + lg*4 + reg;
                float bv = bias[row];
                #pragma unroll
                for(int nf=0; nf<8; nf++){
                    float v2 = (acc[mf][nf][reg] + bv) * msv[nf];
                    v2 = v2 > 0.f ? v2 : 0.f;
                    dst[(size_t)row*HW + hw0 + wn*128 + nf*16 + lr] = f2bf(v2);
                }
            }
        }
    } else {
        unsigned short* dst = OutA + (size_t)bi*CCH*HW;
        #pragma unroll
        for(int mf=0; mf<4; mf++){
            float red[4] = {0.f,0.f,0.f,0.f};
            #pragma unroll
            for(int reg=0; reg<4; reg++){
                int row = wm*64 + mf*16 + lg*4 + reg;
                float bv = biasA[row];
                #pragma unroll
                for(int nf=0; nf<8; nf++){
                    float v2 = (acc[mf][nf][reg] + bv) * msv[nf];
                    v2 = v2 > 0.f ? v2 : 0.f;
                    if constexpr (STORE)
                        dst[(size_t)row*HW + hw0 + wn*128 + nf*16 + lr] = f2bf(v2);
                    red[reg] += v2 * mdv[nf];
                }
            }
            #pragma unroll
            for(int reg=0; reg<4; reg++){
                float r = red[reg];
                r += __shfl_xor(r, 1);
                r += __shfl_xor(r, 2);
                r += __shfl_xor(r, 4);
                r += __shfl_xor(r, 8);
                if(lr == 0)
                    atomicAdd(&xo[(size_t)bg*384 + xo_off + wm*64 + mf*16 + lg*4 + reg], r);
            }
        }
    }
}

// ---------------------------------------------------------------- batched spatial matmul:
// P[b,c] = (A[b,c] @ B[b,c]) * Msum[b]  (128x128x128 bf16 MFMA; P aliases A)
__global__ __launch_bounds__(256) void k_bmm(
    const unsigned short* __restrict__ A, const unsigned short* __restrict__ Bm,
    const float* __restrict__ msum, unsigned short* __restrict__ P, int b0)
{
    __shared__ unsigned short Bs[128*136];
    const int m  = blockIdx.x;
    const int bi = m >> 7;
    const int bg = b0 + bi;
    const unsigned short* Ab = A  + (size_t)m*HW;
    const unsigned short* Bb = Bm + (size_t)m*HW;
    unsigned short*       Pb = P  + (size_t)m*HW;
    const float* ms = msum + (size_t)bg*HW;
    const int t = threadIdx.x;
    const int w  = t >> 6;
    const int l  = t & 63;
    const int lr = l & 15;
    const int lg = l >> 4;

    bf16x8 af[4][2];
    #pragma unroll
    for(int kk=0;kk<4;kk++)
        #pragma unroll
        for(int rt=0;rt<2;rt++)
            af[kk][rt] = *reinterpret_cast<const bf16x8*>(Ab + (size_t)(w*32 + rt*16 + lr)*128 + kk*32 + lg*8);

    #pragma unroll
    for(int it=0; it<8; it++){
        int task = it*256 + t;
        int j  = task & 127;
        int kg = task >> 7;
        unsigned short v[8];
        #pragma unroll
        for(int i=0;i<8;i++) v[i] = Bb[(size_t)(kg*8+i)*128 + j];
        uint4 pk;
        pk.x = (unsigned int)v[0] | ((unsigned int)v[1]<<16);
        pk.y = (unsigned int)v[2] | ((unsigned int)v[3]<<16);
        pk.z = (unsigned int)v[4] | ((unsigned int)v[5]<<16);
        pk.w = (unsigned int)v[6] | ((unsigned int)v[7]<<16);
        *reinterpret_cast<uint4*>(&Bs[j*136 + kg*8]) = pk;
    }
    __syncthreads();

    f32x4 acc[2][8];
    #pragma unroll
    for(int rt=0;rt<2;rt++)
        #pragma unroll
        for(int ct=0;ct<8;ct++) acc[rt][ct] = (f32x4){0.f,0.f,0.f,0.f};

    #pragma unroll
    for(int kk=0;kk<4;kk++){
        #pragma unroll
        for(int ct=0;ct<8;ct++){
            bf16x8 bfr = *reinterpret_cast<const bf16x8*>(&Bs[(ct*16+lr)*136 + kk*32 + lg*8]);
            acc[0][ct] = __builtin_amdgcn_mfma_f32_16x16x32_bf16(af[kk][0], bfr, acc[0][ct], 0,0,0);
            acc[1][ct] = __builtin_amdgcn_mfma_f32_16x16x32_bf16(af[kk][1], bfr, acc[1][ct], 0,0,0);
        }
    }
    #pragma unroll
    for(int rt=0;rt<2;rt++){
        #pragma unroll
        for(int ct=0;ct<8;ct++){
            #pragma unroll
            for(int r=0;r<4;r++){
                int row = w*32 + rt*16 + lg*4 + r;
                int col = ct*16 + lr;
                float v = acc[rt][ct][r] * ms[row*128 + col];
                Pb[(size_t)row*128 + col] = f2bf(v);
            }
        }
    }
}

// ---------------------------------------------------------------- head
__global__ __launch_bounds__(1024) void k_head(
    const float* __restrict__ xo, const float* __restrict__ h1w, const float* __restrict__ h1b,
    const float* __restrict__ h2w, const float* __restrict__ h2b, float* __restrict__ out)
{
    __shared__ float hbuf[NBATCH][32];
    const int t = threadIdx.x;
    const int b = t >> 5, j = t & 31;
    float a = h1b[j];
    #pragma unroll 8
    for(int k=0;k<384;k++) a += xo[b*384+k]*h1w[j*384+k];
    a = a > 0.f ? a : 0.f;
    hbuf[b][j] = a;
    __syncthreads();
    if(j == 0){
        float s = h2b[0];
        #pragma unroll
        for(int k=0;k<32;k++) s += hbuf[b][k]*h2w[k];
        out[b] = s;
    }
}

// ----------------------------------------------------------------
extern "C" void kernel_launch(void* const* d_in, const int* in_sizes, int n_in,
                              void* d_out, int out_size, void* d_ws, size_t ws_size,
                              hipStream_t stream)
{
    (void)in_sizes; (void)n_in; (void)out_size;
    const float* X2  = (const float*)d_in[0];
    const float* M   = (const float*)d_in[1];
    const float* w11 = (const float*)d_in[2];  const float* b11 = (const float*)d_in[3];
    const float* w12 = (const float*)d_in[4];  const float* b12 = (const float*)d_in[5];
    const float* w13 = (const float*)d_in[6];  const float* b13 = (const float*)d_in[7];
    const float* w21 = (const float*)d_in[8];  const float* b21 = (const float*)d_in[9];
    const float* w22 = (const float*)d_in[10]; const float* b22 = (const float*)d_in[11];
    const float* w23 = (const float*)d_in[12]; const float* b23 = (const float*)d_in[13];
    const float* w31 = (const float*)d_in[14]; const float* b31 = (const float*)d_in[15];
    const float* w32 = (const float*)d_in[16]; const float* b32 = (const float*)d_in[17];
    const float* w33 = (const float*)d_in[18]; const float* b33 = (const float*)d_in[19];
    const float* h1w = (const float*)d_in[20]; const float* h1b = (const float*)d_in[21];
    const float* h2w = (const float*)d_in[22]; const float* h2b = (const float*)d_in[23];
    float* out = (float*)d_out;

    char* ws = (char*)d_ws;
    size_t off = 0;
    float* msum = (float*)(ws + off); off += (size_t)NBATCH*HW*4;            // 2 MB
    float* xo   = (float*)(ws + off); off += (size_t)NBATCH*384*4;           // 48 KB
    unsigned short* wp = (unsigned short*)(ws + off); off += (size_t)WPREP_TOTAL*2;  // 780 KB
    off = (off + 255) & ~(size_t)255;

    int bc = 32;
    while (bc > 1 && off + 3ull*(size_t)bc*CCH*HW*2 > ws_size) bc >>= 1;
    size_t bufb = (size_t)bc*CCH*HW*2;
    unsigned short* B0 = (unsigned short*)(ws + off);
    unsigned short* B1 = (unsigned short*)(ws + off + bufb);
    unsigned short* B2 = (unsigned short*)(ws + off + 2*bufb);

    const unsigned short* Wa1 = wp + 0;        // z=1 -> +10240 = wb1
    const unsigned short* Wc1 = wp + 20480;
    const unsigned short* Wa2 = wp + 71680;    // z=1 -> +40960 = wb2
    const unsigned short* Wc2 = wp + 153600;
    const unsigned short* Wa3 = wp + 235520;   // z=1 -> +40960 = wb3
    const unsigned short* Wc3 = wp + 317440;

    // fused: weight prep + msum + xo zero (one node)
    k_setup<<<(NBATCH*HW)/256, 256, 0, stream>>>(
        w11,w12,w13,w21,w22,w23,w31,w32,w33, M, wp, msum, xo);

    for(int b0 = 0; b0 < NBATCH; b0 += bc){
        dim3 gab(HW/256, bc, 2);
        dim3 gcc(HW/256, bc);
        dim3 gmat(bc*CCH);
        // ---- block 1 (X from fp32 X2, in-kernel hi/lo split)
        k_conv<0,1,false,true ,true ><<<gab, 256, 0, stream>>>(Wa1, B0, X2, b11, b12, msum, M, B0, B1, nullptr, b0, 0);
        k_bmm<<<gmat, 256, 0, stream>>>(B0, B1, msum, B0, b0);
        k_conv<4,1,true ,true ,true ><<<gcc, 256, 0, stream>>>(Wc1, B0, X2, b13, b13, msum, M, B1, nullptr, xo, b0, 0);
        // ---- block 2 (X = B1)
        k_conv<0,4,false,false,true ><<<gab, 256, 0, stream>>>(Wa2, B0, B1, b21, b22, msum, M, B2, B0, nullptr, b0, 0);
        k_bmm<<<gmat, 256, 0, stream>>>(B2, B0, msum, B2, b0);
        k_conv<4,4,true ,false,true ><<<gcc, 256, 0, stream>>>(Wc2, B2, B1, b23, b23, msum, M, B0, nullptr, xo, b0, 128);
        // ---- block 3 (X = B0)
        k_conv<0,4,false,false,true ><<<gab, 256, 0, stream>>>(Wa3, B2, B0, b31, b32, msum, M, B1, B2, nullptr, b0, 0);
        k_bmm<<<gmat, 256, 0, stream>>>(B1, B2, msum, B1, b0);
        k_conv<4,4,true ,false,false><<<gcc, 256, 0, stream>>>(Wc3, B1, B0, b33, b33, msum, M, B2, nullptr, xo, b0, 256);
    }
    k_head<<<1, 1024, 0, stream>>>(xo, h1w, h1b, h2w, h2b, out);
}

// Round 14
// 1134.647 us; speedup vs baseline: 4.9032x; 1.0060x over previous
//
#include <hip/hip_runtime.h>
#include <stdint.h>
#include <stddef.h>

#define NBATCH 32
#define HW     16384      // 128*128
#define CCH    128
#define WROW   40         // padded W row stride (shorts)
#define WCHUNK 10240      // [2][128][40] shorts per K-chunk (20 KB)

typedef short bf16x8 __attribute__((ext_vector_type(8)));
typedef float f32x4  __attribute__((ext_vector_type(4)));

__device__ __forceinline__ float bf2f(unsigned short u){
    union { unsigned int i; float f; } v; v.i = ((unsigned int)u) << 16; return v.f;
}
__device__ __forceinline__ unsigned short f2bf(float f){
    union { float f; unsigned int i; } v; v.f = f;
    unsigned int x = v.i;
    x += 0x7fffu + ((x >> 16) & 1u);   // round-to-nearest-even
    return (unsigned short)(x >> 16);
}
__device__ __forceinline__ unsigned int h16(uint2 u, int j){
    unsigned int v = (j & 2) ? u.y : u.x;
    return (j & 1) ? (v >> 16) : (v & 0xffffu);
}
__device__ __forceinline__ void gl_lds16(const unsigned short* g, unsigned short* l){
    __builtin_amdgcn_global_load_lds(
        reinterpret_cast<const __attribute__((address_space(1))) unsigned int*>(
            reinterpret_cast<uintptr_t>(g)),
        reinterpret_cast<__attribute__((address_space(3))) unsigned int*>(
            reinterpret_cast<uintptr_t>(l)),
        16, 0, 0);
}
template<int N> __device__ __forceinline__ void vmwait(){
    asm volatile("s_waitcnt vmcnt(%0)" :: "n"(N) : "memory");
}

// ---------------------------------------------------------------- fused setup:
// weight prep (hi/lo split, [NCH][2][128][40]) + msum + xo zero, one kernel.
#define WPREP_TOTAL 399360
__global__ __launch_bounds__(256) void k_setup(
    const float* __restrict__ w11, const float* __restrict__ w12, const float* __restrict__ w13,
    const float* __restrict__ w21, const float* __restrict__ w22, const float* __restrict__ w23,
    const float* __restrict__ w31, const float* __restrict__ w32, const float* __restrict__ w33,
    const float* __restrict__ M,
    unsigned short* __restrict__ wp, float* __restrict__ msum, float* __restrict__ xo)
{
    int i = blockIdx.x*256 + threadIdx.x;     // grid covers NBATCH*HW = 524288
    {
        int b = i >> 14, hw = i & (HW-1);
        msum[i] = M[(size_t)b*2*HW + hw] + M[(size_t)b*2*HW + HW + hw];
    }
    if(i < NBATCH*384) xo[i] = 0.f;
    if(i < WPREP_TOTAL){
        const float* src; int K, mode, base;
        if     (i < 10240) { src=w11; K=16;  mode=1; base=0;      }
        else if(i < 20480) { src=w12; K=16;  mode=1; base=10240;  }
        else if(i < 71680) { src=w13; K=144; mode=2; base=20480;  }
        else if(i < 112640){ src=w21; K=128; mode=0; base=71680;  }
        else if(i < 153600){ src=w22; K=128; mode=0; base=112640; }
        else if(i < 235520){ src=w23; K=256; mode=0; base=153600; }
        else if(i < 276480){ src=w31; K=128; mode=0; base=235520; }
        else if(i < 317440){ src=w32; K=128; mode=0; base=276480; }
        else               { src=w33; K=256; mode=0; base=317440; }
        int j  = i - base;
        int ck = j / WCHUNK;
        int jj = j - ck*WCHUNK;
        int half = jj / 5120;
        int rr   = (jj / WROW) & 127;
        int c    = jj % WROW;
        float v = 0.f;
        if(c < 32){
            int col = (mode==1) ? (c & 15)
                    : (mode==2) ? (ck < 4 ? ck*32 + c : 128 + (c & 15))
                    :             ck*32 + c;
            v = src[rr*K + col];
        }
        unsigned short hi = f2bf(v);
        wp[i] = half ? f2bf(v - bf2f(hi)) : hi;
    }
}

// ---------------------------------------------------------------- unified conv GEMM (256 thr, 4 waves 2x2)
// Out[128][256-hw] = relu((W @ concat(P,X) + bias)*Msum). KC=32 (x2 hi/lo MFMA).
// !CC: z-twins XCD-paired via blockIdx.x remap (g=x>>4,j=x&15: ht=g*8+(j&7), z=j>>3)
// so both twins (sharing the X tile) land on the same XCD's L2 ~simultaneously.
template<int NCHP, int NCHX, bool CC, bool XS, bool STORE>
__global__ __launch_bounds__(256,2) void k_conv(
    const unsigned short* __restrict__ Wp,
    const unsigned short* __restrict__ Psrc,   // plain [bi][128][HW]
    const void* __restrict__ Xsrc,             // XS: f32 [bg][16][HW]; else bf16 [bi][128][HW]
    const float* __restrict__ biasA, const float* __restrict__ biasB,
    const float* __restrict__ msum, const float* __restrict__ Mfull,
    unsigned short* __restrict__ OutA, unsigned short* __restrict__ OutB,
    float* __restrict__ xo, int b0, int xo_off)
{
    constexpr int NCH = NCHP + NCHX;
    __shared__ unsigned short Wl[2*WCHUNK];    // 40 KB double-buffered W
    __shared__ unsigned short Xt[2*10240];     // 40 KB double-buffered X^T
    const int bi = blockIdx.y, bg = b0 + bi;
    int ht_, z_;
    if constexpr (CC){ ht_ = blockIdx.x; z_ = 0; }
    else {
        const int xb = blockIdx.x;             // 0..127
        const int g = xb >> 4, jj2 = xb & 15;
        ht_ = g*8 + (jj2 & 7);
        z_  = jj2 >> 3;                        // twins 8 apart -> same XCD (n%8)
    }
    const int ht = ht_, z = z_;
    const int hw0 = ht * 256;
    const int t = threadIdx.x;
    const int w = t >> 6, l = t & 63;
    const int lr = l & 15, lg = l >> 4;
    const int wm = w & 1, wn = w >> 1;           // rows wm*64.., cols wn*128..
    const int cg = t & 3, h4 = t >> 2;           // X staging mapping
    const unsigned short* Wseg  = Wp + (size_t)z*NCH*WCHUNK;
    const unsigned short* pbase = Psrc + (size_t)bi*CCH*HW;
    const float* xfbase = nullptr;
    const unsigned short* xbbase = nullptr;
    if constexpr (XS) xfbase = (const float*)Xsrc + (size_t)bg*16*HW;
    else              xbbase = (const unsigned short*)Xsrc + (size_t)bi*CCH*HW;

    f32x4 acc[4][8];
    #pragma unroll
    for(int mf=0; mf<4; mf++)
        #pragma unroll
        for(int nf=0; nf<8; nf++) acc[mf][nf] = (f32x4){0.f,0.f,0.f,0.f};

    uint2 xr0[8], xr1[8];
    float xf0[16], xf1[16];

    auto wdma = [&](int ck){
        const unsigned short* s = Wseg + (size_t)ck*WCHUNK + (size_t)t*8;
        unsigned short* d = &Wl[(ck & 1)*WCHUNK + t*8];
        #pragma unroll
        for(int r=0; r<5; r++)
            gl_lds16(s + (size_t)r*2048, d + r*2048);
    };
    auto loadXb = [&](int ck, uint2 (&xr)[8]){
        const unsigned short* s = ((ck < NCHP) ? (pbase + (size_t)ck*32*HW)
                                               : (xbbase + (size_t)(ck-NCHP)*32*HW))
                                  + hw0 + h4*4;
        #pragma unroll
        for(int i=0;i<8;i++) xr[i] = *reinterpret_cast<const uint2*>(s + (size_t)(cg*8+i)*HW);
    };
    auto loadXf = [&](float (&xf)[16]){
        const float* s = xfbase + hw0 + t;
        #pragma unroll
        for(int c=0;c<16;c++) xf[c] = s[(size_t)c*HW];
    };
    auto writeXb = [&](int buf, uint2 (&xr)[8]){
        #pragma unroll
        for(int j=0;j<4;j++){
            uint4 pk;
            pk.x = h16(xr[0],j) | (h16(xr[1],j) << 16);
            pk.y = h16(xr[2],j) | (h16(xr[3],j) << 16);
            pk.z = h16(xr[4],j) | (h16(xr[5],j) << 16);
            pk.w = h16(xr[6],j) | (h16(xr[7],j) << 16);
            *reinterpret_cast<uint4*>(&Xt[buf*10240 + (h4*4+j)*WROW + cg*8]) = pk;
        }
    };
    auto writeXf = [&](int buf, float (&xf)[16]){
        unsigned int hi[16], lo[16];
        #pragma unroll
        for(int c=0;c<16;c++){
            unsigned short h = f2bf(xf[c]);
            hi[c] = h;
            lo[c] = f2bf(xf[c] - bf2f(h));
        }
        uint4 a, b2, c4, d;
        a.x  = hi[0] |(hi[1] <<16); a.y  = hi[2] |(hi[3] <<16); a.z  = hi[4] |(hi[5] <<16); a.w  = hi[6] |(hi[7] <<16);
        b2.x = hi[8] |(hi[9] <<16); b2.y = hi[10]|(hi[11]<<16); b2.z = hi[12]|(hi[13]<<16); b2.w = hi[14]|(hi[15]<<16);
        c4.x = lo[0] |(lo[1] <<16); c4.y = lo[2] |(lo[3] <<16); c4.z = lo[4] |(lo[5] <<16); c4.w = lo[6] |(lo[7] <<16);
        d.x  = lo[8] |(lo[9] <<16); d.y  = lo[10]|(lo[11]<<16); d.z  = lo[12]|(lo[13]<<16); d.w  = lo[14]|(lo[15]<<16);
        unsigned short* base = &Xt[buf*10240 + t*WROW];
        *reinterpret_cast<uint4*>(base +  0) = a;
        *reinterpret_cast<uint4*>(base +  8) = b2;
        *reinterpret_cast<uint4*>(base + 16) = c4;
        *reinterpret_cast<uint4*>(base + 24) = d;
    };
    auto compute = [&](int buf){
        const unsigned short* Wb = &Wl[buf*WCHUNK];
        const unsigned short* Xb = &Xt[buf*10240];
        bf16x8 ah[4], al[4];
        #pragma unroll
        for(int mf=0; mf<4; mf++){
            ah[mf] = *reinterpret_cast<const bf16x8*>(&Wb[(wm*64 + mf*16 + lr)*WROW + lg*8]);
            al[mf] = *reinterpret_cast<const bf16x8*>(&Wb[(128 + wm*64 + mf*16 + lr)*WROW + lg*8]);
        }
        #pragma unroll
        for(int nf=0; nf<8; nf++){
            bf16x8 bfr = *reinterpret_cast<const bf16x8*>(&Xb[(wn*128 + nf*16 + lr)*WROW + lg*8]);
            #pragma unroll
            for(int mf=0; mf<4; mf++){
                acc[mf][nf] = __builtin_amdgcn_mfma_f32_16x16x32_bf16(ah[mf], bfr, acc[mf][nf], 0,0,0);
                acc[mf][nf] = __builtin_amdgcn_mfma_f32_16x16x32_bf16(al[mf], bfr, acc[mf][nf], 0,0,0);
            }
        }
    };

#define LOADC(CK, S) \
    if constexpr ((CK) < NCHP || !XS){ \
        if constexpr ((S)==0) loadXb((CK), xr0); else loadXb((CK), xr1); \
    } else { \
        if constexpr ((S)==0) loadXf(xf0); else loadXf(xf1); \
    }

    // prologue, issue order: loadX(0) [oldest], wdma(0), loadX(1) [kept at step 0]
    LOADC(0, 0)
    __builtin_amdgcn_sched_barrier(0);
    wdma(0);
    __builtin_amdgcn_sched_barrier(0);
    if constexpr (NCH > 1){ LOADC(1, 1) }
    __builtin_amdgcn_sched_barrier(0);

#define STEP(I) \
    if constexpr ((I) < NCH){ \
        vmwait<(((I)+1 < NCH) ? ((((I)+1) < NCHP) ? 8 : (XS ? 16 : 8)) : 0)>(); \
        __builtin_amdgcn_sched_barrier(0); \
        if constexpr ((I) < NCHP || !XS){ \
            if constexpr (((I)&1)==0) writeXb((I)&1, xr0); else writeXb((I)&1, xr1); \
        } else { \
            if constexpr (((I)&1)==0) writeXf((I)&1, xf0); else writeXf((I)&1, xf1); \
        } \
        asm volatile("s_waitcnt lgkmcnt(0)" ::: "memory"); \
        __builtin_amdgcn_sched_barrier(0); \
        __builtin_amdgcn_s_barrier(); \
        if constexpr ((I)+1 < NCH) wdma((I)+1); \
        __builtin_amdgcn_sched_barrier(0); \
        if constexpr ((I)+2 < NCH){ LOADC((I)+2, (I)&1) } \
        __builtin_amdgcn_sched_barrier(0); \
        __builtin_amdgcn_s_setprio(1); \
        compute((I)&1); \
        __builtin_amdgcn_s_setprio(0); \
    }
    STEP(0) STEP(1) STEP(2) STEP(3) STEP(4) STEP(5) STEP(6) STEP(7)
#undef STEP
#undef LOADC

    // ---- epilogue
    float msv[8], mdv[8];
    #pragma unroll
    for(int nf=0; nf<8; nf++){
        int hwi = hw0 + wn*128 + nf*16 + lr;
        msv[nf] = msum[(size_t)bg*HW + hwi];
        if constexpr (CC) mdv[nf] = Mfull[(size_t)bg*2*HW + hwi];
    }
    if constexpr (!CC){
        const float* bias = z ? biasB : biasA;
        unsigned short* dst = (z ? OutB : OutA) + (size_t)bi*CCH*HW;
        #pragma unroll
        for(int mf=0; mf<4; mf++){
            #pragma unroll
            for(int reg=0; reg<4; reg++){
                int row = wm*64 + mf*16 + lg*4 + reg;
                float bv = bias[row];
                #pragma unroll
                for(int nf=0; nf<8; nf++){
                    float v2 = (acc[mf][nf][reg] + bv) * msv[nf];
                    v2 = v2 > 0.f ? v2 : 0.f;
                    dst[(size_t)row*HW + hw0 + wn*128 + nf*16 + lr] = f2bf(v2);
                }
            }
        }
    } else {
        unsigned short* dst = OutA + (size_t)bi*CCH*HW;
        #pragma unroll
        for(int mf=0; mf<4; mf++){
            float red[4] = {0.f,0.f,0.f,0.f};
            #pragma unroll
            for(int reg=0; reg<4; reg++){
                int row = wm*64 + mf*16 + lg*4 + reg;
                float bv = biasA[row];
                #pragma unroll
                for(int nf=0; nf<8; nf++){
                    float v2 = (acc[mf][nf][reg] + bv) * msv[nf];
                    v2 = v2 > 0.f ? v2 : 0.f;
                    if constexpr (STORE)
                        dst[(size_t)row*HW + hw0 + wn*128 + nf*16 + lr] = f2bf(v2);
                    red[reg] += v2 * mdv[nf];
                }
            }
            #pragma unroll
            for(int reg=0; reg<4; reg++){
                float r = red[reg];
                r += __shfl_xor(r, 1);
                r += __shfl_xor(r, 2);
                r += __shfl_xor(r, 4);
                r += __shfl_xor(r, 8);
                if(lr == 0)
                    atomicAdd(&xo[(size_t)bg*384 + xo_off + wm*64 + mf*16 + lg*4 + reg], r);
            }
        }
    }
}

// ---------------------------------------------------------------- batched spatial matmul:
// P[b,c] = (A[b,c] @ B[b,c]) * Msum[b]  (128x128x128 bf16 MFMA; P aliases A)
__global__ __launch_bounds__(256) void k_bmm(
    const unsigned short* __restrict__ A, const unsigned short* __restrict__ Bm,
    const float* __restrict__ msum, unsigned short* __restrict__ P, int b0)
{
    __shared__ unsigned short Bs[128*136];
    const int m  = blockIdx.x;
    const int bi = m >> 7;
    const int bg = b0 + bi;
    const unsigned short* Ab = A  + (size_t)m*HW;
    const unsigned short* Bb = Bm + (size_t)m*HW;
    unsigned short*       Pb = P  + (size_t)m*HW;
    const float* ms = msum + (size_t)bg*HW;
    const int t = threadIdx.x;
    const int w  = t >> 6;
    const int l  = t & 63;
    const int lr = l & 15;
    const int lg = l >> 4;

    bf16x8 af[4][2];
    #pragma unroll
    for(int kk=0;kk<4;kk++)
        #pragma unroll
        for(int rt=0;rt<2;rt++)
            af[kk][rt] = *reinterpret_cast<const bf16x8*>(Ab + (size_t)(w*32 + rt*16 + lr)*128 + kk*32 + lg*8);

    #pragma unroll
    for(int it=0; it<8; it++){
        int task = it*256 + t;
        int j  = task & 127;
        int kg = task >> 7;
        unsigned short v[8];
        #pragma unroll
        for(int i=0;i<8;i++) v[i] = Bb[(size_t)(kg*8+i)*128 + j];
        uint4 pk;
        pk.x = (unsigned int)v[0] | ((unsigned int)v[1]<<16);
        pk.y = (unsigned int)v[2] | ((unsigned int)v[3]<<16);
        pk.z = (unsigned int)v[4] | ((unsigned int)v[5]<<16);
        pk.w = (unsigned int)v[6] | ((unsigned int)v[7]<<16);
        *reinterpret_cast<uint4*>(&Bs[j*136 + kg*8]) = pk;
    }
    __syncthreads();

    f32x4 acc[2][8];
    #pragma unroll
    for(int rt=0;rt<2;rt++)
        #pragma unroll
        for(int ct=0;ct<8;ct++) acc[rt][ct] = (f32x4){0.f,0.f,0.f,0.f};

    #pragma unroll
    for(int kk=0;kk<4;kk++){
        #pragma unroll
        for(int ct=0;ct<8;ct++){
            bf16x8 bfr = *reinterpret_cast<const bf16x8*>(&Bs[(ct*16+lr)*136 + kk*32 + lg*8]);
            acc[0][ct] = __builtin_amdgcn_mfma_f32_16x16x32_bf16(af[kk][0], bfr, acc[0][ct], 0,0,0);
            acc[1][ct] = __builtin_amdgcn_mfma_f32_16x16x32_bf16(af[kk][1], bfr, acc[1][ct], 0,0,0);
        }
    }
    #pragma unroll
    for(int rt=0;rt<2;rt++){
        #pragma unroll
        for(int ct=0;ct<8;ct++){
            #pragma unroll
            for(int r=0;r<4;r++){
                int row = w*32 + rt*16 + lg*4 + r;
                int col = ct*16 + lr;
                float v = acc[rt][ct][r] * ms[row*128 + col];
                Pb[(size_t)row*128 + col] = f2bf(v);
            }
        }
    }
}

// ---------------------------------------------------------------- head
__global__ __launch_bounds__(1024) void k_head(
    const float* __restrict__ xo, const float* __restrict__ h1w, const float* __restrict__ h1b,
    const float* __restrict__ h2w, const float* __restrict__ h2b, float* __restrict__ out)
{
    __shared__ float hbuf[NBATCH][32];
    const int t = threadIdx.x;
    const int b = t >> 5, j = t & 31;
    float a = h1b[j];
    #pragma unroll 8
    for(int k=0;k<384;k++) a += xo[b*384+k]*h1w[j*384+k];
    a = a > 0.f ? a : 0.f;
    hbuf[b][j] = a;
    __syncthreads();
    if(j == 0){
        float s = h2b[0];
        #pragma unroll
        for(int k=0;k<32;k++) s += hbuf[b][k]*h2w[k];
        out[b] = s;
    }
}

// ----------------------------------------------------------------
extern "C" void kernel_launch(void* const* d_in, const int* in_sizes, int n_in,
                              void* d_out, int out_size, void* d_ws, size_t ws_size,
                              hipStream_t stream)
{
    (void)in_sizes; (void)n_in; (void)out_size;
    const float* X2  = (const float*)d_in[0];
    const float* M   = (const float*)d_in[1];
    const float* w11 = (const float*)d_in[2];  const float* b11 = (const float*)d_in[3];
    const float* w12 = (const float*)d_in[4];  const float* b12 = (const float*)d_in[5];
    const float* w13 = (const float*)d_in[6];  const float* b13 = (const float*)d_in[7];
    const float* w21 = (const float*)d_in[8];  const float* b21 = (const float*)d_in[9];
    const float* w22 = (const float*)d_in[10]; const float* b22 = (const float*)d_in[11];
    const float* w23 = (const float*)d_in[12]; const float* b23 = (const float*)d_in[13];
    const float* w31 = (const float*)d_in[14]; const float* b31 = (const float*)d_in[15];
    const float* w32 = (const float*)d_in[16]; const float* b32 = (const float*)d_in[17];
    const float* w33 = (const float*)d_in[18]; const float* b33 = (const float*)d_in[19];
    const float* h1w = (const float*)d_in[20]; const float* h1b = (const float*)d_in[21];
    const float* h2w = (const float*)d_in[22]; const float* h2b = (const float*)d_in[23];
    float* out = (float*)d_out;

    char* ws = (char*)d_ws;
    size_t off = 0;
    float* msum = (float*)(ws + off); off += (size_t)NBATCH*HW*4;            // 2 MB
    float* xo   = (float*)(ws + off); off += (size_t)NBATCH*384*4;           // 48 KB
    unsigned short* wp = (unsigned short*)(ws + off); off += (size_t)WPREP_TOTAL*2;  // 780 KB
    off = (off + 255) & ~(size_t)255;

    int bc = 32;
    while (bc > 1 && off + 3ull*(size_t)bc*CCH*HW*2 > ws_size) bc >>= 1;
    size_t bufb = (size_t)bc*CCH*HW*2;
    unsigned short* B0 = (unsigned short*)(ws + off);
    unsigned short* B1 = (unsigned short*)(ws + off + bufb);
    unsigned short* B2 = (unsigned short*)(ws + off + 2*bufb);

    const unsigned short* Wa1 = wp + 0;        // z=1 -> +10240 = wb1
    const unsigned short* Wc1 = wp + 20480;
    const unsigned short* Wa2 = wp + 71680;    // z=1 -> +40960 = wb2
    const unsigned short* Wc2 = wp + 153600;
    const unsigned short* Wa3 = wp + 235520;   // z=1 -> +40960 = wb3
    const unsigned short* Wc3 = wp + 317440;

    // fused: weight prep + msum + xo zero (one node)
    k_setup<<<(NBATCH*HW)/256, 256, 0, stream>>>(
        w11,w12,w13,w21,w22,w23,w31,w32,w33, M, wp, msum, xo);

    for(int b0 = 0; b0 < NBATCH; b0 += bc){
        dim3 gab(128, bc);     // z folded into x with XCD-pairing remap (twins 8 apart)
        dim3 gcc(HW/256, bc);
        dim3 gmat(bc*CCH);
        // ---- block 1 (X from fp32 X2, in-kernel hi/lo split)
        k_conv<0,1,false,true ,true ><<<gab, 256, 0, stream>>>(Wa1, B0, X2, b11, b12, msum, M, B0, B1, nullptr, b0, 0);
        k_bmm<<<gmat, 256, 0, stream>>>(B0, B1, msum, B0, b0);
        k_conv<4,1,true ,true ,true ><<<gcc, 256, 0, stream>>>(Wc1, B0, X2, b13, b13, msum, M, B1, nullptr, xo, b0, 0);
        // ---- block 2 (X = B1)
        k_conv<0,4,false,false,true ><<<gab, 256, 0, stream>>>(Wa2, B0, B1, b21, b22, msum, M, B2, B0, nullptr, b0, 0);
        k_bmm<<<gmat, 256, 0, stream>>>(B2, B0, msum, B2, b0);
        k_conv<4,4,true ,false,true ><<<gcc, 256, 0, stream>>>(Wc2, B2, B1, b23, b23, msum, M, B0, nullptr, xo, b0, 128);
        // ---- block 3 (X = B0)
        k_conv<0,4,false,false,true ><<<gab, 256, 0, stream>>>(Wa3, B2, B0, b31, b32, msum, M, B1, B2, nullptr, b0, 0);
        k_bmm<<<gmat, 256, 0, stream>>>(B1, B2, msum, B1, b0);
        k_conv<4,4,true ,false,false><<<gcc, 256, 0, stream>>>(Wc3, B1, B0, b33, b33, msum, M, B2, nullptr, xo, b0, 256);
    }
    k_head<<<1, 1024, 0, stream>>>(xo, h1w, h1b, h2w, h2b, out);
}

// Round 15
// 1133.339 us; speedup vs baseline: 4.9089x; 1.0012x over previous
//
#include <hip/hip_runtime.h>
#include <stdint.h>
#include <stddef.h>

#define NBATCH 32
#define HW     16384      // 128*128
#define CCH    128
#define WROW   40         // padded W row stride (shorts)
#define WCHUNK 10240      // [2][128][40] shorts per K-chunk (20 KB)

typedef short bf16x8 __attribute__((ext_vector_type(8)));
typedef float f32x4  __attribute__((ext_vector_type(4)));

__device__ __forceinline__ float bf2f(unsigned short u){
    union { unsigned int i; float f; } v; v.i = ((unsigned int)u) << 16; return v.f;
}
__device__ __forceinline__ unsigned short f2bf(float f){
    union { float f; unsigned int i; } v; v.f = f;
    unsigned int x = v.i;
    x += 0x7fffu + ((x >> 16) & 1u);   // round-to-nearest-even
    return (unsigned short)(x >> 16);
}
__device__ __forceinline__ unsigned int h16(uint2 u, int j){
    unsigned int v = (j & 2) ? u.y : u.x;
    return (j & 1) ? (v >> 16) : (v & 0xffffu);
}
__device__ __forceinline__ void gl_lds16(const unsigned short* g, unsigned short* l){
    __builtin_amdgcn_global_load_lds(
        reinterpret_cast<const __attribute__((address_space(1))) unsigned int*>(
            reinterpret_cast<uintptr_t>(g)),
        reinterpret_cast<__attribute__((address_space(3))) unsigned int*>(
            reinterpret_cast<uintptr_t>(l)),
        16, 0, 0);
}
template<int N> __device__ __forceinline__ void vmwait(){
    asm volatile("s_waitcnt vmcnt(%0)" :: "n"(N) : "memory");
}

// ---------------------------------------------------------------- fused setup:
// weight prep (hi/lo split, [NCH][2][128][40]) + msum + xo zero, one kernel.
#define WPREP_TOTAL 399360
__global__ __launch_bounds__(256) void k_setup(
    const float* __restrict__ w11, const float* __restrict__ w12, const float* __restrict__ w13,
    const float* __restrict__ w21, const float* __restrict__ w22, const float* __restrict__ w23,
    const float* __restrict__ w31, const float* __restrict__ w32, const float* __restrict__ w33,
    const float* __restrict__ M,
    unsigned short* __restrict__ wp, float* __restrict__ msum, float* __restrict__ xo)
{
    int i = blockIdx.x*256 + threadIdx.x;     // grid covers NBATCH*HW = 524288
    {
        int b = i >> 14, hw = i & (HW-1);
        msum[i] = M[(size_t)b*2*HW + hw] + M[(size_t)b*2*HW + HW + hw];
    }
    if(i < NBATCH*384) xo[i] = 0.f;
    if(i < WPREP_TOTAL){
        const float* src; int K, mode, base;
        if     (i < 10240) { src=w11; K=16;  mode=1; base=0;      }
        else if(i < 20480) { src=w12; K=16;  mode=1; base=10240;  }
        else if(i < 71680) { src=w13; K=144; mode=2; base=20480;  }
        else if(i < 112640){ src=w21; K=128; mode=0; base=71680;  }
        else if(i < 153600){ src=w22; K=128; mode=0; base=112640; }
        else if(i < 235520){ src=w23; K=256; mode=0; base=153600; }
        else if(i < 276480){ src=w31; K=128; mode=0; base=235520; }
        else if(i < 317440){ src=w32; K=128; mode=0; base=276480; }
        else               { src=w33; K=256; mode=0; base=317440; }
        int j  = i - base;
        int ck = j / WCHUNK;
        int jj = j - ck*WCHUNK;
        int half = jj / 5120;
        int rr   = (jj / WROW) & 127;
        int c    = jj % WROW;
        float v = 0.f;
        if(c < 32){
            int col = (mode==1) ? (c & 15)
                    : (mode==2) ? (ck < 4 ? ck*32 + c : 128 + (c & 15))
                    :             ck*32 + c;
            v = src[rr*K + col];
        }
        unsigned short hi = f2bf(v);
        wp[i] = half ? f2bf(v - bf2f(hi)) : hi;
    }
}

// ---------------------------------------------------------------- merged-z conv a+b (512 thr, 8 waves)
// waves 0-3: z=0 (wa->OutA), waves 4-7: z=1 (wb->OutB); X staged ONCE in shared LDS.
// W staged for both z per chunk (dbuf 80KB); Xt dbuf (40KB); 1 barrier/chunk, counted vmcnt.
template<int NCH, bool XS>
__global__ __launch_bounds__(512,2) void k_cab2(
    const unsigned short* __restrict__ Wp,     // [2z][NCH][2][128][40]
    const void* __restrict__ Xsrc,             // XS: f32 [bg][16][HW]; else bf16 [bi][128][HW]
    const float* __restrict__ biasA, const float* __restrict__ biasB,
    const float* __restrict__ msum,
    unsigned short* __restrict__ OutA, unsigned short* __restrict__ OutB, int b0)
{
    __shared__ unsigned short Wl[2*2*WCHUNK];  // [buf][z][WCHUNK] = 80 KB
    __shared__ unsigned short Xt[2*10240];     // [buf][256][40]   = 40 KB
    const int bi = blockIdx.y, bg = b0 + bi;
    const int ht = blockIdx.x;
    const int hw0 = ht * 256;
    const int t = threadIdx.x;
    const int w = t >> 6, l = t & 63;
    const int lr = l & 15, lg = l >> 4;
    const int z  = w >> 2;
    const int wsub = w & 3;
    const int wm = wsub & 1, wn = wsub >> 1;     // rows wm*64.., cols wn*128..
    const int cgx = t & 7, h4x = t >> 3;         // Xb staging: 8 ch-groups of 4, 64 hw-groups of 4
    const float* xfbase = nullptr;
    const unsigned short* xbbase = nullptr;
    if constexpr (XS) xfbase = (const float*)Xsrc + (size_t)bg*16*HW;
    else              xbbase = (const unsigned short*)Xsrc + (size_t)bi*CCH*HW;

    f32x4 acc[4][8];
    #pragma unroll
    for(int mf=0; mf<4; mf++)
        #pragma unroll
        for(int nf=0; nf<8; nf++) acc[mf][nf] = (f32x4){0.f,0.f,0.f,0.f};

    uint2 xr0[4], xr1[4];
    float xf0[8], xf1[8];

    auto wdma = [&](int ck){                     // stages BOTH z segs: 5 x 16B/thread
        #pragma unroll
        for(int r=0; r<5; r++){
            int idx = r*512 + t;                 // 0..2559; seg boundary 1280 (wave-uniform)
            int seg = idx / 1280;
            int off = (idx - seg*1280) * 8;
            gl_lds16(Wp + (size_t)seg*NCH*WCHUNK + (size_t)ck*WCHUNK + off,
                     &Wl[(ck & 1)*2*WCHUNK + seg*WCHUNK + off]);
        }
    };
    auto loadXb = [&](int ck, uint2 (&xr)[4]){
        const unsigned short* s = xbbase + (size_t)ck*32*HW + hw0 + h4x*4;
        #pragma unroll
        for(int i=0;i<4;i++) xr[i] = *reinterpret_cast<const uint2*>(s + (size_t)(cgx*4+i)*HW);
    };
    auto loadXf = [&](float (&xf)[8]){
        const int c0 = (t >> 8) * 8;             // threads 0-255: ch 0-7; 256-511: ch 8-15
        const float* s = xfbase + hw0 + (t & 255);
        #pragma unroll
        for(int c=0;c<8;c++) xf[c] = s[(size_t)(c0+c)*HW];
    };
    auto writeXb = [&](int buf, uint2 (&xr)[4]){
        #pragma unroll
        for(int j=0;j<4;j++){
            uint2 v;
            v.x = h16(xr[0],j) | (h16(xr[1],j) << 16);
            v.y = h16(xr[2],j) | (h16(xr[3],j) << 16);
            *reinterpret_cast<uint2*>(&Xt[buf*10240 + (h4x*4+j)*WROW + cgx*4]) = v;
        }
    };
    auto writeXf = [&](int buf, float (&xf)[8]){
        const int c0 = (t >> 8) * 8;
        const int hwl = t & 255;
        unsigned int hi[8], lo[8];
        #pragma unroll
        for(int c=0;c<8;c++){
            unsigned short h = f2bf(xf[c]);
            hi[c] = h;
            lo[c] = f2bf(xf[c] - bf2f(h));
        }
        uint4 a, b2;
        a.x  = hi[0]|(hi[1]<<16); a.y  = hi[2]|(hi[3]<<16); a.z  = hi[4]|(hi[5]<<16); a.w  = hi[6]|(hi[7]<<16);
        b2.x = lo[0]|(lo[1]<<16); b2.y = lo[2]|(lo[3]<<16); b2.z = lo[4]|(lo[5]<<16); b2.w = lo[6]|(lo[7]<<16);
        unsigned short* base = &Xt[buf*10240 + hwl*WROW];
        *reinterpret_cast<uint4*>(base + c0)      = a;    // hi -> ch c0..c0+7
        *reinterpret_cast<uint4*>(base + 16 + c0) = b2;   // lo -> ch 16+c0..
    };
    auto compute = [&](int buf){
        const unsigned short* Wb = &Wl[buf*2*WCHUNK + z*WCHUNK];
        const unsigned short* Xb = &Xt[buf*10240];
        bf16x8 ah[4], al[4];
        #pragma unroll
        for(int mf=0; mf<4; mf++){
            ah[mf] = *reinterpret_cast<const bf16x8*>(&Wb[(wm*64 + mf*16 + lr)*WROW + lg*8]);
            al[mf] = *reinterpret_cast<const bf16x8*>(&Wb[(128 + wm*64 + mf*16 + lr)*WROW + lg*8]);
        }
        #pragma unroll
        for(int nf=0; nf<8; nf++){
            bf16x8 bfr = *reinterpret_cast<const bf16x8*>(&Xb[(wn*128 + nf*16 + lr)*WROW + lg*8]);
            #pragma unroll
            for(int mf=0; mf<4; mf++){
                acc[mf][nf] = __builtin_amdgcn_mfma_f32_16x16x32_bf16(ah[mf], bfr, acc[mf][nf], 0,0,0);
                acc[mf][nf] = __builtin_amdgcn_mfma_f32_16x16x32_bf16(al[mf], bfr, acc[mf][nf], 0,0,0);
            }
        }
    };

#define LOADC2(CK, S) \
    if constexpr (XS){ \
        if constexpr ((S)==0) loadXf(xf0); else loadXf(xf1); \
    } else { \
        if constexpr ((S)==0) loadXb((CK), xr0); else loadXb((CK), xr1); \
    }

    // prologue: loadX(0) [oldest], wdma(0), loadX(1)
    LOADC2(0, 0)
    __builtin_amdgcn_sched_barrier(0);
    wdma(0);
    __builtin_amdgcn_sched_barrier(0);
    if constexpr (NCH > 1){ LOADC2(1, 1) }
    __builtin_amdgcn_sched_barrier(0);

    // per step I in-flight oldest-first: loadX(I)[keep-none], wdma(I)[5], loadX(I+1)[4|8].
    // vmwait keeps only loadX(I+1).
#define STEP(I) \
    if constexpr ((I) < NCH){ \
        vmwait<(((I)+1 < NCH) ? (XS ? 8 : 4) : 0)>(); \
        __builtin_amdgcn_sched_barrier(0); \
        if constexpr (XS){ \
            if constexpr (((I)&1)==0) writeXf((I)&1, xf0); else writeXf((I)&1, xf1); \
        } else { \
            if constexpr (((I)&1)==0) writeXb((I)&1, xr0); else writeXb((I)&1, xr1); \
        } \
        asm volatile("s_waitcnt lgkmcnt(0)" ::: "memory"); \
        __builtin_amdgcn_sched_barrier(0); \
        __builtin_amdgcn_s_barrier(); \
        if constexpr ((I)+1 < NCH) wdma((I)+1); \
        __builtin_amdgcn_sched_barrier(0); \
        if constexpr ((I)+2 < NCH){ LOADC2((I)+2, (I)&1) } \
        __builtin_amdgcn_sched_barrier(0); \
        __builtin_amdgcn_s_setprio(1); \
        compute((I)&1); \
        __builtin_amdgcn_s_setprio(0); \
    }
    STEP(0) STEP(1) STEP(2) STEP(3)
#undef STEP
#undef LOADC2

    // ---- epilogue: bias, *Msum, relu, bf16 store (wave's z selects output)
    float msv[8];
    #pragma unroll
    for(int nf=0; nf<8; nf++)
        msv[nf] = msum[(size_t)bg*HW + hw0 + wn*128 + nf*16 + lr];
    const float* bias = z ? biasB : biasA;
    unsigned short* dst = (z ? OutB : OutA) + (size_t)bi*CCH*HW;
    #pragma unroll
    for(int mf=0; mf<4; mf++){
        #pragma unroll
        for(int reg=0; reg<4; reg++){
            int row = wm*64 + mf*16 + lg*4 + reg;
            float bv = bias[row];
            #pragma unroll
            for(int nf=0; nf<8; nf++){
                float v2 = (acc[mf][nf][reg] + bv) * msv[nf];
                v2 = v2 > 0.f ? v2 : 0.f;
                dst[(size_t)row*HW + hw0 + wn*128 + nf*16 + lr] = f2bf(v2);
            }
        }
    }
}

// ---------------------------------------------------------------- conv c (unchanged R10 body, CC-only use)
template<int NCHP, int NCHX, bool CC, bool XS, bool STORE>
__global__ __launch_bounds__(256,2) void k_conv(
    const unsigned short* __restrict__ Wp,
    const unsigned short* __restrict__ Psrc,   // plain [bi][128][HW]
    const void* __restrict__ Xsrc,             // XS: f32 [bg][16][HW]; else bf16 [bi][128][HW]
    const float* __restrict__ biasA, const float* __restrict__ biasB,
    const float* __restrict__ msum, const float* __restrict__ Mfull,
    unsigned short* __restrict__ OutA, unsigned short* __restrict__ OutB,
    float* __restrict__ xo, int b0, int xo_off)
{
    constexpr int NCH = NCHP + NCHX;
    __shared__ unsigned short Wl[2*WCHUNK];    // 40 KB double-buffered W
    __shared__ unsigned short Xt[2*10240];     // 40 KB double-buffered X^T
    const int bi = blockIdx.y, bg = b0 + bi;
    const int hw0 = blockIdx.x * 256;
    const int z = 0;
    const int t = threadIdx.x;
    const int w = t >> 6, l = t & 63;
    const int lr = l & 15, lg = l >> 4;
    const int wm = w & 1, wn = w >> 1;
    const int cg = t & 3, h4 = t >> 2;
    const unsigned short* Wseg  = Wp + (size_t)z*NCH*WCHUNK;
    const unsigned short* pbase = Psrc + (size_t)bi*CCH*HW;
    const float* xfbase = nullptr;
    const unsigned short* xbbase = nullptr;
    if constexpr (XS) xfbase = (const float*)Xsrc + (size_t)bg*16*HW;
    else              xbbase = (const unsigned short*)Xsrc + (size_t)bi*CCH*HW;

    f32x4 acc[4][8];
    #pragma unroll
    for(int mf=0; mf<4; mf++)
        #pragma unroll
        for(int nf=0; nf<8; nf++) acc[mf][nf] = (f32x4){0.f,0.f,0.f,0.f};

    uint2 xr0[8], xr1[8];
    float xf0[16], xf1[16];

    auto wdma = [&](int ck){
        const unsigned short* s = Wseg + (size_t)ck*WCHUNK + (size_t)t*8;
        unsigned short* d = &Wl[(ck & 1)*WCHUNK + t*8];
        #pragma unroll
        for(int r=0; r<5; r++)
            gl_lds16(s + (size_t)r*2048, d + r*2048);
    };
    auto loadXb = [&](int ck, uint2 (&xr)[8]){
        const unsigned short* s = ((ck < NCHP) ? (pbase + (size_t)ck*32*HW)
                                               : (xbbase + (size_t)(ck-NCHP)*32*HW))
                                  + hw0 + h4*4;
        #pragma unroll
        for(int i=0;i<8;i++) xr[i] = *reinterpret_cast<const uint2*>(s + (size_t)(cg*8+i)*HW);
    };
    auto loadXf = [&](float (&xf)[16]){
        const float* s = xfbase + hw0 + t;
        #pragma unroll
        for(int c=0;c<16;c++) xf[c] = s[(size_t)c*HW];
    };
    auto writeXb = [&](int buf, uint2 (&xr)[8]){
        #pragma unroll
        for(int j=0;j<4;j++){
            uint4 pk;
            pk.x = h16(xr[0],j) | (h16(xr[1],j) << 16);
            pk.y = h16(xr[2],j) | (h16(xr[3],j) << 16);
            pk.z = h16(xr[4],j) | (h16(xr[5],j) << 16);
            pk.w = h16(xr[6],j) | (h16(xr[7],j) << 16);
            *reinterpret_cast<uint4*>(&Xt[buf*10240 + (h4*4+j)*WROW + cg*8]) = pk;
        }
    };
    auto writeXf = [&](int buf, float (&xf)[16]){
        unsigned int hi[16], lo[16];
        #pragma unroll
        for(int c=0;c<16;c++){
            unsigned short h = f2bf(xf[c]);
            hi[c] = h;
            lo[c] = f2bf(xf[c] - bf2f(h));
        }
        uint4 a, b2, c4, d;
        a.x  = hi[0] |(hi[1] <<16); a.y  = hi[2] |(hi[3] <<16); a.z  = hi[4] |(hi[5] <<16); a.w  = hi[6] |(hi[7] <<16);
        b2.x = hi[8] |(hi[9] <<16); b2.y = hi[10]|(hi[11]<<16); b2.z = hi[12]|(hi[13]<<16); b2.w = hi[14]|(hi[15]<<16);
        c4.x = lo[0] |(lo[1] <<16); c4.y = lo[2] |(lo[3] <<16); c4.z = lo[4] |(lo[5] <<16); c4.w = lo[6] |(lo[7] <<16);
        d.x  = lo[8] |(lo[9] <<16); d.y  = lo[10]|(lo[11]<<16); d.z  = lo[12]|(lo[13]<<16); d.w  = lo[14]|(lo[15]<<16);
        unsigned short* base = &Xt[buf*10240 + t*WROW];
        *reinterpret_cast<uint4*>(base +  0) = a;
        *reinterpret_cast<uint4*>(base +  8) = b2;
        *reinterpret_cast<uint4*>(base + 16) = c4;
        *reinterpret_cast<uint4*>(base + 24) = d;
    };
    auto compute = [&](int buf){
        const unsigned short* Wb = &Wl[buf*WCHUNK];
        const unsigned short* Xb = &Xt[buf*10240];
        bf16x8 ah[4], al[4];
        #pragma unroll
        for(int mf=0; mf<4; mf++){
            ah[mf] = *reinterpret_cast<const bf16x8*>(&Wb[(wm*64 + mf*16 + lr)*WROW + lg*8]);
            al[mf] = *reinterpret_cast<const bf16x8*>(&Wb[(128 + wm*64 + mf*16 + lr)*WROW + lg*8]);
        }
        #pragma unroll
        for(int nf=0; nf<8; nf++){
            bf16x8 bfr = *reinterpret_cast<const bf16x8*>(&Xb[(wn*128 + nf*16 + lr)*WROW + lg*8]);
            #pragma unroll
            for(int mf=0; mf<4; mf++){
                acc[mf][nf] = __builtin_amdgcn_mfma_f32_16x16x32_bf16(ah[mf], bfr, acc[mf][nf], 0,0,0);
                acc[mf][nf] = __builtin_amdgcn_mfma_f32_16x16x32_bf16(al[mf], bfr, acc[mf][nf], 0,0,0);
            }
        }
    };

#define LOADC(CK, S) \
    if constexpr ((CK) < NCHP || !XS){ \
        if constexpr ((S)==0) loadXb((CK), xr0); else loadXb((CK), xr1); \
    } else { \
        if constexpr ((S)==0) loadXf(xf0); else loadXf(xf1); \
    }

    LOADC(0, 0)
    __builtin_amdgcn_sched_barrier(0);
    wdma(0);
    __builtin_amdgcn_sched_barrier(0);
    if constexpr (NCH > 1){ LOADC(1, 1) }
    __builtin_amdgcn_sched_barrier(0);

#define STEP(I) \
    if constexpr ((I) < NCH){ \
        vmwait<(((I)+1 < NCH) ? ((((I)+1) < NCHP) ? 8 : (XS ? 16 : 8)) : 0)>(); \
        __builtin_amdgcn_sched_barrier(0); \
        if constexpr ((I) < NCHP || !XS){ \
            if constexpr (((I)&1)==0) writeXb((I)&1, xr0); else writeXb((I)&1, xr1); \
        } else { \
            if constexpr (((I)&1)==0) writeXf((I)&1, xf0); else writeXf((I)&1, xf1); \
        } \
        asm volatile("s_waitcnt lgkmcnt(0)" ::: "memory"); \
        __builtin_amdgcn_sched_barrier(0); \
        __builtin_amdgcn_s_barrier(); \
        if constexpr ((I)+1 < NCH) wdma((I)+1); \
        __builtin_amdgcn_sched_barrier(0); \
        if constexpr ((I)+2 < NCH){ LOADC((I)+2, (I)&1) } \
        __builtin_amdgcn_sched_barrier(0); \
        __builtin_amdgcn_s_setprio(1); \
        compute((I)&1); \
        __builtin_amdgcn_s_setprio(0); \
    }
    STEP(0) STEP(1) STEP(2) STEP(3) STEP(4) STEP(5) STEP(6) STEP(7)
#undef STEP
#undef LOADC

    // ---- epilogue
    float msv[8], mdv[8];
    #pragma unroll
    for(int nf=0; nf<8; nf++){
        int hwi = hw0 + wn*128 + nf*16 + lr;
        msv[nf] = msum[(size_t)bg*HW + hwi];
        if constexpr (CC) mdv[nf] = Mfull[(size_t)bg*2*HW + hwi];
    }
    if constexpr (!CC){
        const float* bias = biasA;
        unsigned short* dst = OutA + (size_t)bi*CCH*HW;
        #pragma unroll
        for(int mf=0; mf<4; mf++){
            #pragma unroll
            for(int reg=0; reg<4; reg++){
                int row = wm*64 + mf*16 + lg*4 + reg;
                float bv = bias[row];
                #pragma unroll
                for(int nf=0; nf<8; nf++){
                    float v2 = (acc[mf][nf][reg] + bv) * msv[nf];
                    v2 = v2 > 0.f ? v2 : 0.f;
                    dst[(size_t)row*HW + hw0 + wn*128 + nf*16 + lr] = f2bf(v2);
                }
            }
        }
        (void)biasB; (void)OutB;
    } else {
        unsigned short* dst = OutA + (size_t)bi*CCH*HW;
        #pragma unroll
        for(int mf=0; mf<4; mf++){
            float red[4] = {0.f,0.f,0.f,0.f};
            #pragma unroll
            for(int reg=0; reg<4; reg++){
                int row = wm*64 + mf*16 + lg*4 + reg;
                float bv = biasA[row];
                #pragma unroll
                for(int nf=0; nf<8; nf++){
                    float v2 = (acc[mf][nf][reg] + bv) * msv[nf];
                    v2 = v2 > 0.f ? v2 : 0.f;
                    if constexpr (STORE)
                        dst[(size_t)row*HW + hw0 + wn*128 + nf*16 + lr] = f2bf(v2);
                    red[reg] += v2 * mdv[nf];
                }
            }
            #pragma unroll
            for(int reg=0; reg<4; reg++){
                float r = red[reg];
                r += __shfl_xor(r, 1);
                r += __shfl_xor(r, 2);
                r += __shfl_xor(r, 4);
                r += __shfl_xor(r, 8);
                if(lr == 0)
                    atomicAdd(&xo[(size_t)bg*384 + xo_off + wm*64 + mf*16 + lg*4 + reg], r);
            }
        }
    }
}

// ---------------------------------------------------------------- batched spatial matmul:
// P[b,c] = (A[b,c] @ B[b,c]) * Msum[b]  (128x128x128 bf16 MFMA; P aliases A)
__global__ __launch_bounds__(256) void k_bmm(
    const unsigned short* __restrict__ A, const unsigned short* __restrict__ Bm,
    const float* __restrict__ msum, unsigned short* __restrict__ P, int b0)
{
    __shared__ unsigned short Bs[128*136];
    const int m  = blockIdx.x;
    const int bi = m >> 7;
    const int bg = b0 + bi;
    const unsigned short* Ab = A  + (size_t)m*HW;
    const unsigned short* Bb = Bm + (size_t)m*HW;
    unsigned short*       Pb = P  + (size_t)m*HW;
    const float* ms = msum + (size_t)bg*HW;
    const int t = threadIdx.x;
    const int w  = t >> 6;
    const int l  = t & 63;
    const int lr = l & 15;
    const int lg = l >> 4;

    bf16x8 af[4][2];
    #pragma unroll
    for(int kk=0;kk<4;kk++)
        #pragma unroll
        for(int rt=0;rt<2;rt++)
            af[kk][rt] = *reinterpret_cast<const bf16x8*>(Ab + (size_t)(w*32 + rt*16 + lr)*128 + kk*32 + lg*8);

    #pragma unroll
    for(int it=0; it<8; it++){
        int task = it*256 + t;
        int j  = task & 127;
        int kg = task >> 7;
        unsigned short v[8];
        #pragma unroll
        for(int i=0;i<8;i++) v[i] = Bb[(size_t)(kg*8+i)*128 + j];
        uint4 pk;
        pk.x = (unsigned int)v[0] | ((unsigned int)v[1]<<16);
        pk.y = (unsigned int)v[2] | ((unsigned int)v[3]<<16);
        pk.z = (unsigned int)v[4] | ((unsigned int)v[5]<<16);
        pk.w = (unsigned int)v[6] | ((unsigned int)v[7]<<16);
        *reinterpret_cast<uint4*>(&Bs[j*136 + kg*8]) = pk;
    }
    __syncthreads();

    f32x4 acc[2][8];
    #pragma unroll
    for(int rt=0;rt<2;rt++)
        #pragma unroll
        for(int ct=0;ct<8;ct++) acc[rt][ct] = (f32x4){0.f,0.f,0.f,0.f};

    #pragma unroll
    for(int kk=0;kk<4;kk++){
        #pragma unroll
        for(int ct=0;ct<8;ct++){
            bf16x8 bfr = *reinterpret_cast<const bf16x8*>(&Bs[(ct*16+lr)*136 + kk*32 + lg*8]);
            acc[0][ct] = __builtin_amdgcn_mfma_f32_16x16x32_bf16(af[kk][0], bfr, acc[0][ct], 0,0,0);
            acc[1][ct] = __builtin_amdgcn_mfma_f32_16x16x32_bf16(af[kk][1], bfr, acc[1][ct], 0,0,0);
        }
    }
    #pragma unroll
    for(int rt=0;rt<2;rt++){
        #pragma unroll
        for(int ct=0;ct<8;ct++){
            #pragma unroll
            for(int r=0;r<4;r++){
                int row = w*32 + rt*16 + lg*4 + r;
                int col = ct*16 + lr;
                float v = acc[rt][ct][r] * ms[row*128 + col];
                Pb[(size_t)row*128 + col] = f2bf(v);
            }
        }
    }
}

// ---------------------------------------------------------------- head
__global__ __launch_bounds__(1024) void k_head(
    const float* __restrict__ xo, const float* __restrict__ h1w, const float* __restrict__ h1b,
    const float* __restrict__ h2w, const float* __restrict__ h2b, float* __restrict__ out)
{
    __shared__ float hbuf[NBATCH][32];
    const int t = threadIdx.x;
    const int b = t >> 5, j = t & 31;
    float a = h1b[j];
    #pragma unroll 8
    for(int k=0;k<384;k++) a += xo[b*384+k]*h1w[j*384+k];
    a = a > 0.f ? a : 0.f;
    hbuf[b][j] = a;
    __syncthreads();
    if(j == 0){
        float s = h2b[0];
        #pragma unroll
        for(int k=0;k<32;k++) s += hbuf[b][k]*h2w[k];
        out[b] = s;
    }
}

// ----------------------------------------------------------------
extern "C" void kernel_launch(void* const* d_in, const int* in_sizes, int n_in,
                              void* d_out, int out_size, void* d_ws, size_t ws_size,
                              hipStream_t stream)
{
    (void)in_sizes; (void)n_in; (void)out_size;
    const float* X2  = (const float*)d_in[0];
    const float* M   = (const float*)d_in[1];
    const float* w11 = (const float*)d_in[2];  const float* b11 = (const float*)d_in[3];
    const float* w12 = (const float*)d_in[4];  const float* b12 = (const float*)d_in[5];
    const float* w13 = (const float*)d_in[6];  const float* b13 = (const float*)d_in[7];
    const float* w21 = (const float*)d_in[8];  const float* b21 = (const float*)d_in[9];
    const float* w22 = (const float*)d_in[10]; const float* b22 = (const float*)d_in[11];
    const float* w23 = (const float*)d_in[12]; const float* b23 = (const float*)d_in[13];
    const float* w31 = (const float*)d_in[14]; const float* b31 = (const float*)d_in[15];
    const float* w32 = (const float*)d_in[16]; const float* b32 = (const float*)d_in[17];
    const float* w33 = (const float*)d_in[18]; const float* b33 = (const float*)d_in[19];
    const float* h1w = (const float*)d_in[20]; const float* h1b = (const float*)d_in[21];
    const float* h2w = (const float*)d_in[22]; const float* h2b = (const float*)d_in[23];
    float* out = (float*)d_out;

    char* ws = (char*)d_ws;
    size_t off = 0;
    float* msum = (float*)(ws + off); off += (size_t)NBATCH*HW*4;            // 2 MB
    float* xo   = (float*)(ws + off); off += (size_t)NBATCH*384*4;           // 48 KB
    unsigned short* wp = (unsigned short*)(ws + off); off += (size_t)WPREP_TOTAL*2;  // 780 KB
    off = (off + 255) & ~(size_t)255;

    int bc = 32;
    while (bc > 1 && off + 3ull*(size_t)bc*CCH*HW*2 > ws_size) bc >>= 1;
    size_t bufb = (size_t)bc*CCH*HW*2;
    unsigned short* B0 = (unsigned short*)(ws + off);
    unsigned short* B1 = (unsigned short*)(ws + off + bufb);
    unsigned short* B2 = (unsigned short*)(ws + off + 2*bufb);

    const unsigned short* Wa1 = wp + 0;        // z=1 -> +10240 = wb1
    const unsigned short* Wc1 = wp + 20480;
    const unsigned short* Wa2 = wp + 71680;    // z=1 -> +40960 = wb2
    const unsigned short* Wc2 = wp + 153600;
    const unsigned short* Wa3 = wp + 235520;   // z=1 -> +40960 = wb3
    const unsigned short* Wc3 = wp + 317440;

    // fused: weight prep + msum + xo zero (one node)
    k_setup<<<(NBATCH*HW)/256, 256, 0, stream>>>(
        w11,w12,w13,w21,w22,w23,w31,w32,w33, M, wp, msum, xo);

    for(int b0 = 0; b0 < NBATCH; b0 += bc){
        dim3 gab(64, bc);          // merged-z: one 8-wave block per (ht,bi)
        dim3 gcc(HW/256, bc);
        dim3 gmat(bc*CCH);
        // ---- block 1 (X from fp32 X2, in-kernel hi/lo split)
        k_cab2<1,true ><<<gab, 512, 0, stream>>>(Wa1, X2, b11, b12, msum, B0, B1, b0);
        k_bmm<<<gmat, 256, 0, stream>>>(B0, B1, msum, B0, b0);
        k_conv<4,1,true ,true ,true ><<<gcc, 256, 0, stream>>>(Wc1, B0, X2, b13, b13, msum, M, B1, nullptr, xo, b0, 0);
        // ---- block 2 (X = B1)
        k_cab2<4,false><<<gab, 512, 0, stream>>>(Wa2, B1, b21, b22, msum, B2, B0, b0);
        k_bmm<<<gmat, 256, 0, stream>>>(B2, B0, msum, B2, b0);
        k_conv<4,4,true ,false,true ><<<gcc, 256, 0, stream>>>(Wc2, B2, B1, b23, b23, msum, M, B0, nullptr, xo, b0, 128);
        // ---- block 3 (X = B0)
        k_cab2<4,false><<<gab, 512, 0, stream>>>(Wa3, B0, b31, b32, msum, B1, B2, b0);
        k_bmm<<<gmat, 256, 0, stream>>>(B1, B2, msum, B1, b0);
        k_conv<4,4,true ,false,false><<<gcc, 256, 0, stream>>>(Wc3, B1, B0, b33, b33, msum, M, B2, nullptr, xo, b0, 256);
    }
    k_head<<<1, 1024, 0, stream>>>(xo, h1w, h1b, h2w, h2b, out);
}